// Round 1
// baseline (812.192 us; speedup 1.0000x reference)
//
#include <hip/hip_runtime.h>
#include <hip/hip_bf16.h>

#define BB 64
#define SS 512
#define II 32
#define HH 64
#define DD 128
#define FF 256
#define NHEAD 8
#define HDIM 16
#define NTOK (SS*BB)   // 32768

__device__ __forceinline__ float fast_tanh(float x) {
    float ax = fabsf(x);
    float e = __expf(-2.0f * ax);
    float r = (1.0f - e) * __builtin_amdgcn_rcpf(1.0f + e);
    return copysignf(r, x);
}

// ---------------- Kernel 1: xw = x @ W_ih^T + b_ih + b_hh, layout (S,B,H) ----
__global__ __launch_bounds__(256) void k_xw(const float* __restrict__ x,
                                            const float* __restrict__ W_ih,
                                            const float* __restrict__ b_ih,
                                            const float* __restrict__ b_hh,
                                            float* __restrict__ xw) {
    int idx = blockIdx.x * 256 + threadIdx.x;  // over S*B*H = 2M
    int j  = idx & (HH - 1);
    int sb = idx >> 6;          // s*B + b
    int s  = sb >> 6;           // / B
    int b  = sb & (BB - 1);
    const float* xr = x + (b * SS + s) * II;
    const float* wr = W_ih + j * II;
    float acc = b_ih[j] + b_hh[j];
    #pragma unroll
    for (int k = 0; k < II; k += 4) {
        float4 xv = *(const float4*)(xr + k);
        float4 wv = *(const float4*)(wr + k);
        acc += xv.x * wv.x + xv.y * wv.y + xv.z * wv.z + xv.w * wv.w;
    }
    xw[idx] = acc;
}

// ---------------- Kernel 2: RNN recurrence, one block (1 wave) per batch ----
__global__ __launch_bounds__(64) void k_rnn(const float* __restrict__ xw,
                                            const float* __restrict__ W_hh,
                                            float* __restrict__ hs) {
    int b = blockIdx.x;
    int j = threadIdx.x;
    float w[HH];
    #pragma unroll
    for (int k = 0; k < HH; k++) w[k] = W_hh[j * HH + k];
    __shared__ float hsm[HH];
    hsm[j] = 0.0f;
    __syncthreads();
    float xv = xw[(0 * BB + b) * HH + j];
    for (int t = 0; t < SS; t++) {
        // prefetch next timestep's x-projection (hides global latency)
        int tn = (t < SS - 1) ? t + 1 : t;
        float xnext = xw[(tn * BB + b) * HH + j];
        float acc = xv;
        #pragma unroll
        for (int k = 0; k < HH; k++) acc += w[k] * hsm[k];
        float hv = fast_tanh(acc);
        __syncthreads();
        hsm[j] = hv;
        hs[(t * BB + b) * HH + j] = hv;
        __syncthreads();
        xv = xnext;
    }
}

// ---------------- Kernel 3: tiled GEMM  C[M,N] = A[M,K] @ W[N,K]^T + bias ----
// 64x64 tile per 256-thread block; LDS staged transposed [k][row] so the
// inner loop is 2 x ds_read_b128 + 16 FMA per k (FMA-bound).
template<int K, bool RELU>
__global__ __launch_bounds__(256) void k_gemm(const float* __restrict__ A,
                                              const float* __restrict__ W,
                                              const float* __restrict__ bias,
                                              float* __restrict__ C, int N) {
    __shared__ float As[32][68];
    __shared__ float Ws[32][68];
    int tid = threadIdx.x;
    int tx = tid & 15, ty = tid >> 4;
    int rowBase = blockIdx.x * 64, colBase = blockIdx.y * 64;

    float acc[4][4];
    #pragma unroll
    for (int j2 = 0; j2 < 4; j2++) {
        float bv = bias[colBase + tx * 4 + j2];
        #pragma unroll
        for (int i2 = 0; i2 < 4; i2++) acc[i2][j2] = bv;
    }

    for (int kb = 0; kb < K; kb += 32) {
        #pragma unroll
        for (int u = 0; u < 2; u++) {
            int f = tid + u * 256;       // 0..511
            int r = f >> 3;              // 0..63
            int kk = (f & 7) * 4;
            float4 av = *(const float4*)(A + (size_t)(rowBase + r) * K + kb + kk);
            float4 wv = *(const float4*)(W + (size_t)(colBase + r) * K + kb + kk);
            As[kk + 0][r] = av.x; As[kk + 1][r] = av.y;
            As[kk + 2][r] = av.z; As[kk + 3][r] = av.w;
            Ws[kk + 0][r] = wv.x; Ws[kk + 1][r] = wv.y;
            Ws[kk + 2][r] = wv.z; Ws[kk + 3][r] = wv.w;
        }
        __syncthreads();
        #pragma unroll
        for (int kk = 0; kk < 32; kk++) {
            float4 a = *(const float4*)(&As[kk][ty * 4]);
            float4 w = *(const float4*)(&Ws[kk][tx * 4]);
            acc[0][0] += a.x * w.x; acc[0][1] += a.x * w.y;
            acc[0][2] += a.x * w.z; acc[0][3] += a.x * w.w;
            acc[1][0] += a.y * w.x; acc[1][1] += a.y * w.y;
            acc[1][2] += a.y * w.z; acc[1][3] += a.y * w.w;
            acc[2][0] += a.z * w.x; acc[2][1] += a.z * w.y;
            acc[2][2] += a.z * w.z; acc[2][3] += a.z * w.w;
            acc[3][0] += a.w * w.x; acc[3][1] += a.w * w.y;
            acc[3][2] += a.w * w.z; acc[3][3] += a.w * w.w;
        }
        __syncthreads();
    }
    #pragma unroll
    for (int i2 = 0; i2 < 4; i2++) {
        float4 o;
        o.x = acc[i2][0]; o.y = acc[i2][1]; o.z = acc[i2][2]; o.w = acc[i2][3];
        if (RELU) {
            o.x = fmaxf(o.x, 0.f); o.y = fmaxf(o.y, 0.f);
            o.z = fmaxf(o.z, 0.f); o.w = fmaxf(o.w, 0.f);
        }
        *(float4*)(C + (size_t)(rowBase + ty * 4 + i2) * N + colBase + tx * 4) = o;
    }
}

// ---------------- Kernel 4: flash attention, one block per (b, head) --------
__global__ __launch_bounds__(256) void k_attn(const float* __restrict__ qkv,
                                              float* __restrict__ ctx) {
    int bh = blockIdx.x;
    int b = bh >> 3, h = bh & 7;
    __shared__ float Ks[SS][HDIM];  // 32KB
    __shared__ float Vs[SS][HDIM];  // 32KB
    int tid = threadIdx.x;
    for (int r = tid; r < SS; r += 256) {
        const float* src = qkv + (size_t)(r * BB + b) * 384;
        #pragma unroll
        for (int c = 0; c < 4; c++) {
            *(float4*)&Ks[r][c * 4] = *(const float4*)(src + 128 + h * 16 + c * 4);
            *(float4*)&Vs[r][c * 4] = *(const float4*)(src + 256 + h * 16 + c * 4);
        }
    }
    __syncthreads();

    const float scale = 0.25f;  // 1/sqrt(16)
    int s0 = tid, s1 = tid + 256;
    const float* q0p = qkv + (size_t)(s0 * BB + b) * 384 + h * 16;
    const float* q1p = qkv + (size_t)(s1 * BB + b) * 384 + h * 16;
    float q0[16], q1[16];
    #pragma unroll
    for (int c = 0; c < 16; c += 4) {
        *(float4*)&q0[c] = *(const float4*)(q0p + c);
        *(float4*)&q1[c] = *(const float4*)(q1p + c);
    }
    float m0 = -1e30f, l0 = 0.f, m1 = -1e30f, l1 = 0.f;
    float acc0[16], acc1[16];
    #pragma unroll
    for (int d = 0; d < 16; d++) { acc0[d] = 0.f; acc1[d] = 0.f; }

    for (int t = 0; t < SS; t++) {
        float kr[16];
        #pragma unroll
        for (int c = 0; c < 16; c += 4) *(float4*)&kr[c] = *(const float4*)&Ks[t][c];
        float sa = 0.f, sb = 0.f;
        #pragma unroll
        for (int d = 0; d < 16; d++) { sa += q0[d] * kr[d]; sb += q1[d] * kr[d]; }
        sa *= scale; sb *= scale;

        float vr[16];
        #pragma unroll
        for (int c = 0; c < 16; c += 4) *(float4*)&vr[c] = *(const float4*)&Vs[t][c];

        if (sa > m0) {
            float cr = __expf(m0 - sa);
            l0 *= cr;
            #pragma unroll
            for (int d = 0; d < 16; d++) acc0[d] *= cr;
            m0 = sa;
        }
        float p0 = __expf(sa - m0);
        l0 += p0;
        #pragma unroll
        for (int d = 0; d < 16; d++) acc0[d] += p0 * vr[d];

        if (sb > m1) {
            float cr = __expf(m1 - sb);
            l1 *= cr;
            #pragma unroll
            for (int d = 0; d < 16; d++) acc1[d] *= cr;
            m1 = sb;
        }
        float p1 = __expf(sb - m1);
        l1 += p1;
        #pragma unroll
        for (int d = 0; d < 16; d++) acc1[d] += p1 * vr[d];
    }
    float inv0 = __builtin_amdgcn_rcpf(l0);
    float inv1 = __builtin_amdgcn_rcpf(l1);
    float* o0 = ctx + (size_t)(s0 * BB + b) * DD + h * 16;
    float* o1 = ctx + (size_t)(s1 * BB + b) * DD + h * 16;
    #pragma unroll
    for (int c = 0; c < 4; c++) {
        float4 v0, v1;
        v0.x = acc0[c*4+0]*inv0; v0.y = acc0[c*4+1]*inv0;
        v0.z = acc0[c*4+2]*inv0; v0.w = acc0[c*4+3]*inv0;
        v1.x = acc1[c*4+0]*inv1; v1.y = acc1[c*4+1]*inv1;
        v1.z = acc1[c*4+2]*inv1; v1.w = acc1[c*4+3]*inv1;
        *(float4*)(o0 + c * 4) = v0;
        *(float4*)(o1 + c * 4) = v1;
    }
}

// ---------------- Kernel 5: out = LayerNorm(a + b) * g + be (row = D=128) ---
__global__ __launch_bounds__(256) void k_add_ln(const float* __restrict__ a,
                                                const float* __restrict__ bres,
                                                const float* __restrict__ g,
                                                const float* __restrict__ be,
                                                float* __restrict__ out) {
    int row = blockIdx.x * 4 + (threadIdx.x >> 6);
    int lane = threadIdx.x & 63;
    const float* ar = a + (size_t)row * DD;
    const float* br = bres + (size_t)row * DD;
    float v0 = ar[lane] + br[lane];
    float v1 = ar[lane + 64] + br[lane + 64];
    float sum = v0 + v1;
    #pragma unroll
    for (int off = 32; off; off >>= 1) sum += __shfl_xor(sum, off, 64);
    float mu = sum * (1.0f / 128.0f);
    float d0 = v0 - mu, d1 = v1 - mu;
    float vs = d0 * d0 + d1 * d1;
    #pragma unroll
    for (int off = 32; off; off >>= 1) vs += __shfl_xor(vs, off, 64);
    float rstd = rsqrtf(vs * (1.0f / 128.0f) + 1e-5f);
    float* orow = out + (size_t)row * DD;
    orow[lane]      = d0 * rstd * g[lane] + be[lane];
    orow[lane + 64] = d1 * rstd * g[lane + 64] + be[lane + 64];
}

// ---------------- Kernel 6: mean-pool over S --------------------------------
__global__ __launch_bounds__(128) void k_pool(const float* __restrict__ out_ln,
                                              float* __restrict__ pooled) {
    int b = blockIdx.x;
    int d = threadIdx.x;
    float sum = 0.f;
    #pragma unroll 8
    for (int s = 0; s < SS; s++) sum += out_ln[(size_t)(s * BB + b) * DD + d];
    pooled[b * DD + d] = sum * (1.0f / SS);
}

// ---------------- Kernel 7: head  out = tanh(pooled @ Wf^T + bf) ------------
__global__ __launch_bounds__(64) void k_final(const float* __restrict__ pooled,
                                              const float* __restrict__ Wf,
                                              const float* __restrict__ bf,
                                              float* __restrict__ out) {
    int idx = blockIdx.x * 64 + threadIdx.x;  // 2048
    int b = idx >> 5, i = idx & 31;
    const float* pr = pooled + b * DD;
    const float* wr = Wf + i * DD;
    float acc = bf[i];
    #pragma unroll
    for (int k = 0; k < DD; k += 4) {
        float4 p = *(const float4*)(pr + k);
        float4 w = *(const float4*)(wr + k);
        acc += p.x * w.x + p.y * w.y + p.z * w.z + p.w * w.w;
    }
    out[idx] = fast_tanh(acc);
}

extern "C" void kernel_launch(void* const* d_in, const int* in_sizes, int n_in,
                              void* d_out, int out_size, void* d_ws, size_t ws_size,
                              hipStream_t stream) {
    const float* x    = (const float*)d_in[0];
    const float* W_ih = (const float*)d_in[1];
    const float* b_ih = (const float*)d_in[2];
    const float* W_hh = (const float*)d_in[3];
    const float* b_hh = (const float*)d_in[4];
    const float* Wp   = (const float*)d_in[5];
    const float* bp   = (const float*)d_in[6];
    const float* Wqkv = (const float*)d_in[7];
    const float* bqkv = (const float*)d_in[8];
    const float* Wo   = (const float*)d_in[9];
    const float* bo   = (const float*)d_in[10];
    const float* g1   = (const float*)d_in[11];
    const float* be1  = (const float*)d_in[12];
    const float* W1   = (const float*)d_in[13];
    const float* b1   = (const float*)d_in[14];
    const float* W2   = (const float*)d_in[15];
    const float* b2   = (const float*)d_in[16];
    const float* g2   = (const float*)d_in[17];
    const float* be2  = (const float*)d_in[18];
    const float* gn   = (const float*)d_in[19];
    const float* bn   = (const float*)d_in[20];
    const float* Wf   = (const float*)d_in[21];
    const float* bf   = (const float*)d_in[22];
    float* out = (float*)d_out;
    float* ws  = (float*)d_ws;

    // workspace layout (floats); regions reused once dead. Needs ~128.1 MB.
    float* proj     = ws + 0;          // 4M   [phase 3 .. end]
    float* qkv      = ws + 4194304;    // 12.6M [phase 4 .. 5]
    float* outln    = ws + 4194304;    // 4M   (reuses qkv, phase 11+)
    float* x2       = ws + 8388608;    // 4M   (reuses qkv, phase 10+)
    float* xw       = ws + 16777216;   // 2M   [phase 1 .. 2]
    float* hsbuf    = ws + 18874368;   // 2M   [phase 2 .. 3]
    float* ctx      = ws + 16777216;   // 4M   (reuses xw+hs, phase 5 .. 6)
    float* ff2      = ws + 16777216;   // 4M   (reuses ctx, phase 9 .. 10)
    float* x1       = ws + 20971520;   // 4M   [phase 7 .. 10]
    float* attn_out = ws + 25165824;   // 4M   [phase 6 .. 7]
    float* ff1      = ws + 25165824;   // 8.4M (reuses attn_out, phase 8 .. 9)
    float* pooled   = ws + 33554432;   // 8K

    k_xw<<<8192, 256, 0, stream>>>(x, W_ih, b_ih, b_hh, xw);
    k_rnn<<<64, 64, 0, stream>>>(xw, W_hh, hsbuf);
    k_gemm<64,  false><<<dim3(512, 2), 256, 0, stream>>>(hsbuf, Wp, bp, proj, 128);
    k_gemm<128, false><<<dim3(512, 6), 256, 0, stream>>>(proj, Wqkv, bqkv, qkv, 384);
    k_attn<<<512, 256, 0, stream>>>(qkv, ctx);
    k_gemm<128, false><<<dim3(512, 2), 256, 0, stream>>>(ctx, Wo, bo, attn_out, 128);
    k_add_ln<<<8192, 256, 0, stream>>>(proj, attn_out, g1, be1, x1);
    k_gemm<128, true ><<<dim3(512, 4), 256, 0, stream>>>(x1, W1, b1, ff1, 256);
    k_gemm<256, false><<<dim3(512, 2), 256, 0, stream>>>(ff1, W2, b2, ff2, 128);
    k_add_ln<<<8192, 256, 0, stream>>>(x1, ff2, g2, be2, x2);
    k_add_ln<<<8192, 256, 0, stream>>>(x2, proj, gn, bn, outln);
    k_pool<<<64, 128, 0, stream>>>(outln, pooled);
    k_final<<<32, 64, 0, stream>>>(pooled, Wf, bf, out);
}

// Round 2
// 747.192 us; speedup vs baseline: 1.0870x; 1.0870x over previous
//
#include <hip/hip_runtime.h>
#include <hip/hip_bf16.h>

#define BB 64
#define SS 512
#define II 32
#define HH 64
#define DD 128
#define FF 256
#define NHEAD 8
#define HDIM 16
#define NTOK (SS*BB)   // 32768

__device__ __forceinline__ float fast_tanh(float x) {
    float ax = fabsf(x);
    float e = __expf(-2.0f * ax);
    float r = (1.0f - e) * __builtin_amdgcn_rcpf(1.0f + e);
    return copysignf(r, x);
}

// broadcast lane `lane`'s value of v to all lanes (const lane -> v_readlane_b32)
__device__ __forceinline__ float bcast(float v, int lane) {
    return __int_as_float(__builtin_amdgcn_readlane(__float_as_int(v), lane));
}

// ---------------- Kernel 1: xw = x @ W_ih^T + b_ih + b_hh, layout (S,B,H) ----
__global__ __launch_bounds__(256) void k_xw(const float* __restrict__ x,
                                            const float* __restrict__ W_ih,
                                            const float* __restrict__ b_ih,
                                            const float* __restrict__ b_hh,
                                            float* __restrict__ xw) {
    int idx = blockIdx.x * 256 + threadIdx.x;  // over S*B*H = 2M
    int j  = idx & (HH - 1);
    int sb = idx >> 6;          // s*B + b
    int s  = sb >> 6;           // / B
    int b  = sb & (BB - 1);
    const float* xr = x + (b * SS + s) * II;
    const float* wr = W_ih + j * II;
    float acc = b_ih[j] + b_hh[j];
    #pragma unroll
    for (int k = 0; k < II; k += 4) {
        float4 xv = *(const float4*)(xr + k);
        float4 wv = *(const float4*)(wr + k);
        acc += xv.x * wv.x + xv.y * wv.y + xv.z * wv.z + xv.w * wv.w;
    }
    xw[idx] = acc;
}

// ---------------- Kernel 2: RNN recurrence, one block (1 wave) per batch ----
// h lives in registers: lane j holds h[j]. Cross-lane broadcast via
// v_readlane_b32 (constant lane) -- no LDS, no __syncthreads, so no
// vmcnt(0)/lgkmcnt(0) barrier drains on the critical path. The hs store is
// fire-and-forget. 4 independent FMA accumulator chains break the 256-cycle
// dependent-add chain into ~64 cycles of latency.
__global__ __launch_bounds__(64) void k_rnn(const float* __restrict__ xw,
                                            const float* __restrict__ W_hh,
                                            float* __restrict__ hs) {
    int b = blockIdx.x;
    int j = threadIdx.x;
    float w[HH];
    #pragma unroll
    for (int k = 0; k < HH; k++) w[k] = W_hh[j * HH + k];

    float hv = 0.0f;
    float xv = xw[(0 * BB + b) * HH + j];
    for (int t = 0; t < SS; t++) {
        int tn = (t < SS - 1) ? t + 1 : t;
        float xnext = xw[(tn * BB + b) * HH + j];  // prefetch, never barrier-drained
        float a0 = xv, a1 = 0.f, a2 = 0.f, a3 = 0.f;
        #pragma unroll
        for (int k = 0; k < HH; k += 4) {
            a0 = fmaf(w[k + 0], bcast(hv, k + 0), a0);
            a1 = fmaf(w[k + 1], bcast(hv, k + 1), a1);
            a2 = fmaf(w[k + 2], bcast(hv, k + 2), a2);
            a3 = fmaf(w[k + 3], bcast(hv, k + 3), a3);
        }
        hv = fast_tanh((a0 + a1) + (a2 + a3));
        hs[(t * BB + b) * HH + j] = hv;   // fire-and-forget
        xv = xnext;
    }
}

// ---------------- Kernel 3: tiled GEMM  C[M,N] = A[M,K] @ W[N,K]^T + bias ----
// 64x64 tile per 256-thread block; LDS staged transposed [k][row] so the
// inner loop is 2 x ds_read_b128 + 16 FMA per k (FMA-bound).
template<int K, bool RELU>
__global__ __launch_bounds__(256) void k_gemm(const float* __restrict__ A,
                                              const float* __restrict__ W,
                                              const float* __restrict__ bias,
                                              float* __restrict__ C, int N) {
    __shared__ float As[32][68];
    __shared__ float Ws[32][68];
    int tid = threadIdx.x;
    int tx = tid & 15, ty = tid >> 4;
    int rowBase = blockIdx.x * 64, colBase = blockIdx.y * 64;

    float acc[4][4];
    #pragma unroll
    for (int j2 = 0; j2 < 4; j2++) {
        float bv = bias[colBase + tx * 4 + j2];
        #pragma unroll
        for (int i2 = 0; i2 < 4; i2++) acc[i2][j2] = bv;
    }

    for (int kb = 0; kb < K; kb += 32) {
        #pragma unroll
        for (int u = 0; u < 2; u++) {
            int f = tid + u * 256;       // 0..511
            int r = f >> 3;              // 0..63
            int kk = (f & 7) * 4;
            float4 av = *(const float4*)(A + (size_t)(rowBase + r) * K + kb + kk);
            float4 wv = *(const float4*)(W + (size_t)(colBase + r) * K + kb + kk);
            As[kk + 0][r] = av.x; As[kk + 1][r] = av.y;
            As[kk + 2][r] = av.z; As[kk + 3][r] = av.w;
            Ws[kk + 0][r] = wv.x; Ws[kk + 1][r] = wv.y;
            Ws[kk + 2][r] = wv.z; Ws[kk + 3][r] = wv.w;
        }
        __syncthreads();
        #pragma unroll
        for (int kk = 0; kk < 32; kk++) {
            float4 a = *(const float4*)(&As[kk][ty * 4]);
            float4 w = *(const float4*)(&Ws[kk][tx * 4]);
            acc[0][0] += a.x * w.x; acc[0][1] += a.x * w.y;
            acc[0][2] += a.x * w.z; acc[0][3] += a.x * w.w;
            acc[1][0] += a.y * w.x; acc[1][1] += a.y * w.y;
            acc[1][2] += a.y * w.z; acc[1][3] += a.y * w.w;
            acc[2][0] += a.z * w.x; acc[2][1] += a.z * w.y;
            acc[2][2] += a.z * w.z; acc[2][3] += a.z * w.w;
            acc[3][0] += a.w * w.x; acc[3][1] += a.w * w.y;
            acc[3][2] += a.w * w.z; acc[3][3] += a.w * w.w;
        }
        __syncthreads();
    }
    #pragma unroll
    for (int i2 = 0; i2 < 4; i2++) {
        float4 o;
        o.x = acc[i2][0]; o.y = acc[i2][1]; o.z = acc[i2][2]; o.w = acc[i2][3];
        if (RELU) {
            o.x = fmaxf(o.x, 0.f); o.y = fmaxf(o.y, 0.f);
            o.z = fmaxf(o.z, 0.f); o.w = fmaxf(o.w, 0.f);
        }
        *(float4*)(C + (size_t)(rowBase + ty * 4 + i2) * N + colBase + tx * 4) = o;
    }
}

// ---------------- Kernel 4: flash attention, one block per (b, head) --------
__global__ __launch_bounds__(256) void k_attn(const float* __restrict__ qkv,
                                              float* __restrict__ ctx) {
    int bh = blockIdx.x;
    int b = bh >> 3, h = bh & 7;
    __shared__ float Ks[SS][HDIM];  // 32KB
    __shared__ float Vs[SS][HDIM];  // 32KB
    int tid = threadIdx.x;
    for (int r = tid; r < SS; r += 256) {
        const float* src = qkv + (size_t)(r * BB + b) * 384;
        #pragma unroll
        for (int c = 0; c < 4; c++) {
            *(float4*)&Ks[r][c * 4] = *(const float4*)(src + 128 + h * 16 + c * 4);
            *(float4*)&Vs[r][c * 4] = *(const float4*)(src + 256 + h * 16 + c * 4);
        }
    }
    __syncthreads();

    const float scale = 0.25f;  // 1/sqrt(16)
    int s0 = tid, s1 = tid + 256;
    const float* q0p = qkv + (size_t)(s0 * BB + b) * 384 + h * 16;
    const float* q1p = qkv + (size_t)(s1 * BB + b) * 384 + h * 16;
    float q0[16], q1[16];
    #pragma unroll
    for (int c = 0; c < 16; c += 4) {
        *(float4*)&q0[c] = *(const float4*)(q0p + c);
        *(float4*)&q1[c] = *(const float4*)(q1p + c);
    }
    float m0 = -1e30f, l0 = 0.f, m1 = -1e30f, l1 = 0.f;
    float acc0[16], acc1[16];
    #pragma unroll
    for (int d = 0; d < 16; d++) { acc0[d] = 0.f; acc1[d] = 0.f; }

    for (int t = 0; t < SS; t++) {
        float kr[16];
        #pragma unroll
        for (int c = 0; c < 16; c += 4) *(float4*)&kr[c] = *(const float4*)&Ks[t][c];
        float sa = 0.f, sb = 0.f;
        #pragma unroll
        for (int d = 0; d < 16; d++) { sa += q0[d] * kr[d]; sb += q1[d] * kr[d]; }
        sa *= scale; sb *= scale;

        float vr[16];
        #pragma unroll
        for (int c = 0; c < 16; c += 4) *(float4*)&vr[c] = *(const float4*)&Vs[t][c];

        if (sa > m0) {
            float cr = __expf(m0 - sa);
            l0 *= cr;
            #pragma unroll
            for (int d = 0; d < 16; d++) acc0[d] *= cr;
            m0 = sa;
        }
        float p0 = __expf(sa - m0);
        l0 += p0;
        #pragma unroll
        for (int d = 0; d < 16; d++) acc0[d] += p0 * vr[d];

        if (sb > m1) {
            float cr = __expf(m1 - sb);
            l1 *= cr;
            #pragma unroll
            for (int d = 0; d < 16; d++) acc1[d] *= cr;
            m1 = sb;
        }
        float p1 = __expf(sb - m1);
        l1 += p1;
        #pragma unroll
        for (int d = 0; d < 16; d++) acc1[d] += p1 * vr[d];
    }
    float inv0 = __builtin_amdgcn_rcpf(l0);
    float inv1 = __builtin_amdgcn_rcpf(l1);
    float* o0 = ctx + (size_t)(s0 * BB + b) * DD + h * 16;
    float* o1 = ctx + (size_t)(s1 * BB + b) * DD + h * 16;
    #pragma unroll
    for (int c = 0; c < 4; c++) {
        float4 v0, v1;
        v0.x = acc0[c*4+0]*inv0; v0.y = acc0[c*4+1]*inv0;
        v0.z = acc0[c*4+2]*inv0; v0.w = acc0[c*4+3]*inv0;
        v1.x = acc1[c*4+0]*inv1; v1.y = acc1[c*4+1]*inv1;
        v1.z = acc1[c*4+2]*inv1; v1.w = acc1[c*4+3]*inv1;
        *(float4*)(o0 + c * 4) = v0;
        *(float4*)(o1 + c * 4) = v1;
    }
}

// ---------------- Kernel 5: out = LayerNorm(a + b) * g + be (row = D=128) ---
__global__ __launch_bounds__(256) void k_add_ln(const float* __restrict__ a,
                                                const float* __restrict__ bres,
                                                const float* __restrict__ g,
                                                const float* __restrict__ be,
                                                float* __restrict__ out) {
    int row = blockIdx.x * 4 + (threadIdx.x >> 6);
    int lane = threadIdx.x & 63;
    const float* ar = a + (size_t)row * DD;
    const float* br = bres + (size_t)row * DD;
    float v0 = ar[lane] + br[lane];
    float v1 = ar[lane + 64] + br[lane + 64];
    float sum = v0 + v1;
    #pragma unroll
    for (int off = 32; off; off >>= 1) sum += __shfl_xor(sum, off, 64);
    float mu = sum * (1.0f / 128.0f);
    float d0 = v0 - mu, d1 = v1 - mu;
    float vs = d0 * d0 + d1 * d1;
    #pragma unroll
    for (int off = 32; off; off >>= 1) vs += __shfl_xor(vs, off, 64);
    float rstd = rsqrtf(vs * (1.0f / 128.0f) + 1e-5f);
    float* orow = out + (size_t)row * DD;
    orow[lane]      = d0 * rstd * g[lane] + be[lane];
    orow[lane + 64] = d1 * rstd * g[lane + 64] + be[lane + 64];
}

// ---------------- Kernel 6: mean-pool over S --------------------------------
__global__ __launch_bounds__(128) void k_pool(const float* __restrict__ out_ln,
                                              float* __restrict__ pooled) {
    int b = blockIdx.x;
    int d = threadIdx.x;
    float sum = 0.f;
    #pragma unroll 8
    for (int s = 0; s < SS; s++) sum += out_ln[(size_t)(s * BB + b) * DD + d];
    pooled[b * DD + d] = sum * (1.0f / SS);
}

// ---------------- Kernel 7: head  out = tanh(pooled @ Wf^T + bf) ------------
__global__ __launch_bounds__(64) void k_final(const float* __restrict__ pooled,
                                              const float* __restrict__ Wf,
                                              const float* __restrict__ bf,
                                              float* __restrict__ out) {
    int idx = blockIdx.x * 64 + threadIdx.x;  // 2048
    int b = idx >> 5, i = idx & 31;
    const float* pr = pooled + b * DD;
    const float* wr = Wf + i * DD;
    float acc = bf[i];
    #pragma unroll
    for (int k = 0; k < DD; k += 4) {
        float4 p = *(const float4*)(pr + k);
        float4 w = *(const float4*)(wr + k);
        acc += p.x * w.x + p.y * w.y + p.z * w.z + p.w * w.w;
    }
    out[idx] = fast_tanh(acc);
}

extern "C" void kernel_launch(void* const* d_in, const int* in_sizes, int n_in,
                              void* d_out, int out_size, void* d_ws, size_t ws_size,
                              hipStream_t stream) {
    const float* x    = (const float*)d_in[0];
    const float* W_ih = (const float*)d_in[1];
    const float* b_ih = (const float*)d_in[2];
    const float* W_hh = (const float*)d_in[3];
    const float* b_hh = (const float*)d_in[4];
    const float* Wp   = (const float*)d_in[5];
    const float* bp   = (const float*)d_in[6];
    const float* Wqkv = (const float*)d_in[7];
    const float* bqkv = (const float*)d_in[8];
    const float* Wo   = (const float*)d_in[9];
    const float* bo   = (const float*)d_in[10];
    const float* g1   = (const float*)d_in[11];
    const float* be1  = (const float*)d_in[12];
    const float* W1   = (const float*)d_in[13];
    const float* b1   = (const float*)d_in[14];
    const float* W2   = (const float*)d_in[15];
    const float* b2   = (const float*)d_in[16];
    const float* g2   = (const float*)d_in[17];
    const float* be2  = (const float*)d_in[18];
    const float* gn   = (const float*)d_in[19];
    const float* bn   = (const float*)d_in[20];
    const float* Wf   = (const float*)d_in[21];
    const float* bf   = (const float*)d_in[22];
    float* out = (float*)d_out;
    float* ws  = (float*)d_ws;

    // workspace layout (floats); regions reused once dead. Needs ~128.1 MB.
    float* proj     = ws + 0;          // 4M   [phase 3 .. end]
    float* qkv      = ws + 4194304;    // 12.6M [phase 4 .. 5]
    float* outln    = ws + 4194304;    // 4M   (reuses qkv, phase 11+)
    float* x2       = ws + 8388608;    // 4M   (reuses qkv, phase 10+)
    float* xw       = ws + 16777216;   // 2M   [phase 1 .. 2]
    float* hsbuf    = ws + 18874368;   // 2M   [phase 2 .. 3]
    float* ctx      = ws + 16777216;   // 4M   (reuses xw+hs, phase 5 .. 6)
    float* ff2      = ws + 16777216;   // 4M   (reuses ctx, phase 9 .. 10)
    float* x1       = ws + 20971520;   // 4M   [phase 7 .. 10]
    float* attn_out = ws + 25165824;   // 4M   [phase 6 .. 7]
    float* ff1      = ws + 25165824;   // 8.4M (reuses attn_out, phase 8 .. 9)
    float* pooled   = ws + 33554432;   // 8K

    k_xw<<<8192, 256, 0, stream>>>(x, W_ih, b_ih, b_hh, xw);
    k_rnn<<<64, 64, 0, stream>>>(xw, W_hh, hsbuf);
    k_gemm<64,  false><<<dim3(512, 2), 256, 0, stream>>>(hsbuf, Wp, bp, proj, 128);
    k_gemm<128, false><<<dim3(512, 6), 256, 0, stream>>>(proj, Wqkv, bqkv, qkv, 384);
    k_attn<<<512, 256, 0, stream>>>(qkv, ctx);
    k_gemm<128, false><<<dim3(512, 2), 256, 0, stream>>>(ctx, Wo, bo, attn_out, 128);
    k_add_ln<<<8192, 256, 0, stream>>>(proj, attn_out, g1, be1, x1);
    k_gemm<128, true ><<<dim3(512, 4), 256, 0, stream>>>(x1, W1, b1, ff1, 256);
    k_gemm<256, false><<<dim3(512, 2), 256, 0, stream>>>(ff1, W2, b2, ff2, 128);
    k_add_ln<<<8192, 256, 0, stream>>>(x1, ff2, g2, be2, x2);
    k_add_ln<<<8192, 256, 0, stream>>>(x2, proj, gn, bn, outln);
    k_pool<<<64, 128, 0, stream>>>(outln, pooled);
    k_final<<<32, 64, 0, stream>>>(pooled, Wf, bf, out);
}

// Round 3
// 637.272 us; speedup vs baseline: 1.2745x; 1.1725x over previous
//
#include <hip/hip_runtime.h>
#include <hip/hip_bf16.h>

#define BB 64
#define SS 512
#define II 32
#define HH 64
#define DD 128
#define FF 256
#define NHEAD 8
#define HDIM 16
#define NTOK (SS*BB)   // 32768

__device__ __forceinline__ float fast_tanh(float x) {
    float ax = fabsf(x);
    float e = __expf(-2.0f * ax);
    float r = (1.0f - e) * __builtin_amdgcn_rcpf(1.0f + e);
    return copysignf(r, x);
}

// broadcast lane `lane`'s value of v to all lanes (const lane -> v_readlane_b32)
__device__ __forceinline__ float bcast(float v, int lane) {
    return __int_as_float(__builtin_amdgcn_readlane(__float_as_int(v), lane));
}

// ---------------- Kernel 1: xw = x @ W_ih^T + b_ih + b_hh, layout (S,B,H) ----
__global__ __launch_bounds__(256) void k_xw(const float* __restrict__ x,
                                            const float* __restrict__ W_ih,
                                            const float* __restrict__ b_ih,
                                            const float* __restrict__ b_hh,
                                            float* __restrict__ xw) {
    int idx = blockIdx.x * 256 + threadIdx.x;  // over S*B*H = 2M
    int j  = idx & (HH - 1);
    int sb = idx >> 6;          // s*B + b
    int s  = sb >> 6;           // / B
    int b  = sb & (BB - 1);
    const float* xr = x + (b * SS + s) * II;
    const float* wr = W_ih + j * II;
    float acc = b_ih[j] + b_hh[j];
    #pragma unroll
    for (int k = 0; k < II; k += 4) {
        float4 xv = *(const float4*)(xr + k);
        float4 wv = *(const float4*)(wr + k);
        acc += xv.x * wv.x + xv.y * wv.y + xv.z * wv.z + xv.w * wv.w;
    }
    xw[idx] = acc;
}

// ---------------- Kernel 2: RNN recurrence, one block (1 wave) per batch ----
// h lives in registers: lane j holds h[j]; broadcast via v_readlane (no LDS,
// no barriers). __launch_bounds__(64, 1): this block is ONE wave and only 64
// blocks exist, so occupancy is irrelevant -- raise the VGPR budget to 512 so
// the 64-entry W_hh row stays RESIDENT in VGPRs. (At the default budget the
// compiler allocated 48 VGPRs and rematerialized the W row from global memory
// every timestep -- R2 profile: VALUBusy 2.4%, 90% of each step stalled.)
// xw is prefetched 2 steps ahead to cover L2/L3 latency (~500 cyc > 1 step).
__global__ __launch_bounds__(64, 1) void k_rnn(const float* __restrict__ xw,
                                               const float* __restrict__ W_hh,
                                               float* __restrict__ hs) {
    int b = blockIdx.x;
    int j = threadIdx.x;
    float w[HH];
    #pragma unroll
    for (int k = 0; k < HH; k++) w[k] = W_hh[j * HH + k];

    float hv = 0.0f;
    float xv0 = xw[(0 * BB + b) * HH + j];
    float xv1 = xw[(1 * BB + b) * HH + j];
    for (int t = 0; t < SS; t++) {
        int tn = (t < SS - 2) ? t + 2 : t;
        float xnext = xw[(tn * BB + b) * HH + j];  // prefetch depth 2
        float a0 = xv0, a1 = 0.f, a2 = 0.f, a3 = 0.f;
        #pragma unroll
        for (int k = 0; k < HH; k += 4) {
            a0 = fmaf(w[k + 0], bcast(hv, k + 0), a0);
            a1 = fmaf(w[k + 1], bcast(hv, k + 1), a1);
            a2 = fmaf(w[k + 2], bcast(hv, k + 2), a2);
            a3 = fmaf(w[k + 3], bcast(hv, k + 3), a3);
        }
        hv = fast_tanh((a0 + a1) + (a2 + a3));
        hs[(t * BB + b) * HH + j] = hv;   // fire-and-forget
        xv0 = xv1;
        xv1 = xnext;
    }
}

// ---------------- Kernel 3: tiled GEMM  C[M,N] = A[M,K] @ W[N,K]^T + bias ----
// 64x64 tile per 256-thread block; LDS staged transposed [k][row] so the
// inner loop is 2 x ds_read_b128 + 16 FMA per k (FMA-bound).
template<int K, bool RELU>
__global__ __launch_bounds__(256) void k_gemm(const float* __restrict__ A,
                                              const float* __restrict__ W,
                                              const float* __restrict__ bias,
                                              float* __restrict__ C, int N) {
    __shared__ float As[32][68];
    __shared__ float Ws[32][68];
    int tid = threadIdx.x;
    int tx = tid & 15, ty = tid >> 4;
    int rowBase = blockIdx.x * 64, colBase = blockIdx.y * 64;

    float acc[4][4];
    #pragma unroll
    for (int j2 = 0; j2 < 4; j2++) {
        float bv = bias[colBase + tx * 4 + j2];
        #pragma unroll
        for (int i2 = 0; i2 < 4; i2++) acc[i2][j2] = bv;
    }

    for (int kb = 0; kb < K; kb += 32) {
        #pragma unroll
        for (int u = 0; u < 2; u++) {
            int f = tid + u * 256;       // 0..511
            int r = f >> 3;              // 0..63
            int kk = (f & 7) * 4;
            float4 av = *(const float4*)(A + (size_t)(rowBase + r) * K + kb + kk);
            float4 wv = *(const float4*)(W + (size_t)(colBase + r) * K + kb + kk);
            As[kk + 0][r] = av.x; As[kk + 1][r] = av.y;
            As[kk + 2][r] = av.z; As[kk + 3][r] = av.w;
            Ws[kk + 0][r] = wv.x; Ws[kk + 1][r] = wv.y;
            Ws[kk + 2][r] = wv.z; Ws[kk + 3][r] = wv.w;
        }
        __syncthreads();
        #pragma unroll
        for (int kk = 0; kk < 32; kk++) {
            float4 a = *(const float4*)(&As[kk][ty * 4]);
            float4 w = *(const float4*)(&Ws[kk][tx * 4]);
            acc[0][0] += a.x * w.x; acc[0][1] += a.x * w.y;
            acc[0][2] += a.x * w.z; acc[0][3] += a.x * w.w;
            acc[1][0] += a.y * w.x; acc[1][1] += a.y * w.y;
            acc[1][2] += a.y * w.z; acc[1][3] += a.y * w.w;
            acc[2][0] += a.z * w.x; acc[2][1] += a.z * w.y;
            acc[2][2] += a.z * w.z; acc[2][3] += a.z * w.w;
            acc[3][0] += a.w * w.x; acc[3][1] += a.w * w.y;
            acc[3][2] += a.w * w.z; acc[3][3] += a.w * w.w;
        }
        __syncthreads();
    }
    #pragma unroll
    for (int i2 = 0; i2 < 4; i2++) {
        float4 o;
        o.x = acc[i2][0]; o.y = acc[i2][1]; o.z = acc[i2][2]; o.w = acc[i2][3];
        if (RELU) {
            o.x = fmaxf(o.x, 0.f); o.y = fmaxf(o.y, 0.f);
            o.z = fmaxf(o.z, 0.f); o.w = fmaxf(o.w, 0.f);
        }
        *(float4*)(C + (size_t)(rowBase + ty * 4 + i2) * N + colBase + tx * 4) = o;
    }
}

// ---------------- Kernel 4: flash attention, one block per (b, head) --------
__global__ __launch_bounds__(256) void k_attn(const float* __restrict__ qkv,
                                              float* __restrict__ ctx) {
    int bh = blockIdx.x;
    int b = bh >> 3, h = bh & 7;
    __shared__ float Ks[SS][HDIM];  // 32KB
    __shared__ float Vs[SS][HDIM];  // 32KB
    int tid = threadIdx.x;
    for (int r = tid; r < SS; r += 256) {
        const float* src = qkv + (size_t)(r * BB + b) * 384;
        #pragma unroll
        for (int c = 0; c < 4; c++) {
            *(float4*)&Ks[r][c * 4] = *(const float4*)(src + 128 + h * 16 + c * 4);
            *(float4*)&Vs[r][c * 4] = *(const float4*)(src + 256 + h * 16 + c * 4);
        }
    }
    __syncthreads();

    const float scale = 0.25f;  // 1/sqrt(16)
    int s0 = tid, s1 = tid + 256;
    const float* q0p = qkv + (size_t)(s0 * BB + b) * 384 + h * 16;
    const float* q1p = qkv + (size_t)(s1 * BB + b) * 384 + h * 16;
    float q0[16], q1[16];
    #pragma unroll
    for (int c = 0; c < 16; c += 4) {
        *(float4*)&q0[c] = *(const float4*)(q0p + c);
        *(float4*)&q1[c] = *(const float4*)(q1p + c);
    }
    float m0 = -1e30f, l0 = 0.f, m1 = -1e30f, l1 = 0.f;
    float acc0[16], acc1[16];
    #pragma unroll
    for (int d = 0; d < 16; d++) { acc0[d] = 0.f; acc1[d] = 0.f; }

    for (int t = 0; t < SS; t++) {
        float kr[16];
        #pragma unroll
        for (int c = 0; c < 16; c += 4) *(float4*)&kr[c] = *(const float4*)&Ks[t][c];
        float sa = 0.f, sb = 0.f;
        #pragma unroll
        for (int d = 0; d < 16; d++) { sa += q0[d] * kr[d]; sb += q1[d] * kr[d]; }
        sa *= scale; sb *= scale;

        float vr[16];
        #pragma unroll
        for (int c = 0; c < 16; c += 4) *(float4*)&vr[c] = *(const float4*)&Vs[t][c];

        if (sa > m0) {
            float cr = __expf(m0 - sa);
            l0 *= cr;
            #pragma unroll
            for (int d = 0; d < 16; d++) acc0[d] *= cr;
            m0 = sa;
        }
        float p0 = __expf(sa - m0);
        l0 += p0;
        #pragma unroll
        for (int d = 0; d < 16; d++) acc0[d] += p0 * vr[d];

        if (sb > m1) {
            float cr = __expf(m1 - sb);
            l1 *= cr;
            #pragma unroll
            for (int d = 0; d < 16; d++) acc1[d] *= cr;
            m1 = sb;
        }
        float p1 = __expf(sb - m1);
        l1 += p1;
        #pragma unroll
        for (int d = 0; d < 16; d++) acc1[d] += p1 * vr[d];
    }
    float inv0 = __builtin_amdgcn_rcpf(l0);
    float inv1 = __builtin_amdgcn_rcpf(l1);
    float* o0 = ctx + (size_t)(s0 * BB + b) * DD + h * 16;
    float* o1 = ctx + (size_t)(s1 * BB + b) * DD + h * 16;
    #pragma unroll
    for (int c = 0; c < 4; c++) {
        float4 v0, v1;
        v0.x = acc0[c*4+0]*inv0; v0.y = acc0[c*4+1]*inv0;
        v0.z = acc0[c*4+2]*inv0; v0.w = acc0[c*4+3]*inv0;
        v1.x = acc1[c*4+0]*inv1; v1.y = acc1[c*4+1]*inv1;
        v1.z = acc1[c*4+2]*inv1; v1.w = acc1[c*4+3]*inv1;
        *(float4*)(o0 + c * 4) = v0;
        *(float4*)(o1 + c * 4) = v1;
    }
}

// ---------------- Kernel 5: out = LayerNorm(a + b) * g + be (row = D=128) ---
__global__ __launch_bounds__(256) void k_add_ln(const float* __restrict__ a,
                                                const float* __restrict__ bres,
                                                const float* __restrict__ g,
                                                const float* __restrict__ be,
                                                float* __restrict__ out) {
    int row = blockIdx.x * 4 + (threadIdx.x >> 6);
    int lane = threadIdx.x & 63;
    const float* ar = a + (size_t)row * DD;
    const float* br = bres + (size_t)row * DD;
    float v0 = ar[lane] + br[lane];
    float v1 = ar[lane + 64] + br[lane + 64];
    float sum = v0 + v1;
    #pragma unroll
    for (int off = 32; off; off >>= 1) sum += __shfl_xor(sum, off, 64);
    float mu = sum * (1.0f / 128.0f);
    float d0 = v0 - mu, d1 = v1 - mu;
    float vs = d0 * d0 + d1 * d1;
    #pragma unroll
    for (int off = 32; off; off >>= 1) vs += __shfl_xor(vs, off, 64);
    float rstd = rsqrtf(vs * (1.0f / 128.0f) + 1e-5f);
    float* orow = out + (size_t)row * DD;
    orow[lane]      = d0 * rstd * g[lane] + be[lane];
    orow[lane + 64] = d1 * rstd * g[lane + 64] + be[lane + 64];
}

// ---------------- Kernel 6: mean-pool over S --------------------------------
__global__ __launch_bounds__(128) void k_pool(const float* __restrict__ out_ln,
                                              float* __restrict__ pooled) {
    int b = blockIdx.x;
    int d = threadIdx.x;
    float sum = 0.f;
    #pragma unroll 8
    for (int s = 0; s < SS; s++) sum += out_ln[(size_t)(s * BB + b) * DD + d];
    pooled[b * DD + d] = sum * (1.0f / SS);
}

// ---------------- Kernel 7: head  out = tanh(pooled @ Wf^T + bf) ------------
__global__ __launch_bounds__(64) void k_final(const float* __restrict__ pooled,
                                              const float* __restrict__ Wf,
                                              const float* __restrict__ bf,
                                              float* __restrict__ out) {
    int idx = blockIdx.x * 64 + threadIdx.x;  // 2048
    int b = idx >> 5, i = idx & 31;
    const float* pr = pooled + b * DD;
    const float* wr = Wf + i * DD;
    float acc = bf[i];
    #pragma unroll
    for (int k = 0; k < DD; k += 4) {
        float4 p = *(const float4*)(pr + k);
        float4 w = *(const float4*)(wr + k);
        acc += p.x * w.x + p.y * w.y + p.z * w.z + p.w * w.w;
    }
    out[idx] = fast_tanh(acc);
}

extern "C" void kernel_launch(void* const* d_in, const int* in_sizes, int n_in,
                              void* d_out, int out_size, void* d_ws, size_t ws_size,
                              hipStream_t stream) {
    const float* x    = (const float*)d_in[0];
    const float* W_ih = (const float*)d_in[1];
    const float* b_ih = (const float*)d_in[2];
    const float* W_hh = (const float*)d_in[3];
    const float* b_hh = (const float*)d_in[4];
    const float* Wp   = (const float*)d_in[5];
    const float* bp   = (const float*)d_in[6];
    const float* Wqkv = (const float*)d_in[7];
    const float* bqkv = (const float*)d_in[8];
    const float* Wo   = (const float*)d_in[9];
    const float* bo   = (const float*)d_in[10];
    const float* g1   = (const float*)d_in[11];
    const float* be1  = (const float*)d_in[12];
    const float* W1   = (const float*)d_in[13];
    const float* b1   = (const float*)d_in[14];
    const float* W2   = (const float*)d_in[15];
    const float* b2   = (const float*)d_in[16];
    const float* g2   = (const float*)d_in[17];
    const float* be2  = (const float*)d_in[18];
    const float* gn   = (const float*)d_in[19];
    const float* bn   = (const float*)d_in[20];
    const float* Wf   = (const float*)d_in[21];
    const float* bf   = (const float*)d_in[22];
    float* out = (float*)d_out;
    float* ws  = (float*)d_ws;

    // workspace layout (floats); regions reused once dead. Needs ~128.1 MB.
    float* proj     = ws + 0;          // 4M   [phase 3 .. end]
    float* qkv      = ws + 4194304;    // 12.6M [phase 4 .. 5]
    float* outln    = ws + 4194304;    // 4M   (reuses qkv, phase 11+)
    float* x2       = ws + 8388608;    // 4M   (reuses qkv, phase 10+)
    float* xw       = ws + 16777216;   // 2M   [phase 1 .. 2]
    float* hsbuf    = ws + 18874368;   // 2M   [phase 2 .. 3]
    float* ctx      = ws + 16777216;   // 4M   (reuses xw+hs, phase 5 .. 6)
    float* ff2      = ws + 16777216;   // 4M   (reuses ctx, phase 9 .. 10)
    float* x1       = ws + 20971520;   // 4M   [phase 7 .. 10]
    float* attn_out = ws + 25165824;   // 4M   [phase 6 .. 7]
    float* ff1      = ws + 25165824;   // 8.4M (reuses attn_out, phase 8 .. 9)
    float* pooled   = ws + 33554432;   // 8K

    k_xw<<<8192, 256, 0, stream>>>(x, W_ih, b_ih, b_hh, xw);
    k_rnn<<<64, 64, 0, stream>>>(xw, W_hh, hsbuf);
    k_gemm<64,  false><<<dim3(512, 2), 256, 0, stream>>>(hsbuf, Wp, bp, proj, 128);
    k_gemm<128, false><<<dim3(512, 6), 256, 0, stream>>>(proj, Wqkv, bqkv, qkv, 384);
    k_attn<<<512, 256, 0, stream>>>(qkv, ctx);
    k_gemm<128, false><<<dim3(512, 2), 256, 0, stream>>>(ctx, Wo, bo, attn_out, 128);
    k_add_ln<<<8192, 256, 0, stream>>>(proj, attn_out, g1, be1, x1);
    k_gemm<128, true ><<<dim3(512, 4), 256, 0, stream>>>(x1, W1, b1, ff1, 256);
    k_gemm<256, false><<<dim3(512, 2), 256, 0, stream>>>(ff1, W2, b2, ff2, 128);
    k_add_ln<<<8192, 256, 0, stream>>>(x1, ff2, g2, be2, x2);
    k_add_ln<<<8192, 256, 0, stream>>>(x2, proj, gn, bn, outln);
    k_pool<<<64, 128, 0, stream>>>(outln, pooled);
    k_final<<<32, 64, 0, stream>>>(pooled, Wf, bf, out);
}

// Round 4
// 547.011 us; speedup vs baseline: 1.4848x; 1.1650x over previous
//
#include <hip/hip_runtime.h>
#include <hip/hip_bf16.h>

#define BB 64
#define SS 512
#define II 32
#define HH 64
#define DD 128
#define FF 256
#define NHEAD 8
#define HDIM 16
#define NTOK (SS*BB)   // 32768

typedef short bf16x8 __attribute__((ext_vector_type(8)));
typedef float f32x4  __attribute__((ext_vector_type(4)));

__device__ __forceinline__ float fast_tanh(float x) {
    float ax = fabsf(x);
    float e = __expf(-2.0f * ax);
    float r = (1.0f - e) * __builtin_amdgcn_rcpf(1.0f + e);
    return copysignf(r, x);
}

// broadcast lane `lane`'s value of v to all lanes (const lane -> v_readlane_b32)
__device__ __forceinline__ float bcast(float v, int lane) {
    return __int_as_float(__builtin_amdgcn_readlane(__float_as_int(v), lane));
}

// fp32 -> bf16 bits, round-to-nearest-even
__device__ __forceinline__ short f2bf(float x) {
    unsigned u = __float_as_uint(x);
    return (short)((u + 0x7FFFu + ((u >> 16) & 1u)) >> 16);
}

// ---------------- Kernel 1: xw = x @ W_ih^T + b_ih + b_hh, layout (S,B,H) ----
__global__ __launch_bounds__(256) void k_xw(const float* __restrict__ x,
                                            const float* __restrict__ W_ih,
                                            const float* __restrict__ b_ih,
                                            const float* __restrict__ b_hh,
                                            float* __restrict__ xw) {
    int idx = blockIdx.x * 256 + threadIdx.x;  // over S*B*H = 2M
    int j  = idx & (HH - 1);
    int sb = idx >> 6;          // s*B + b
    int s  = sb >> 6;           // / B
    int b  = sb & (BB - 1);
    const float* xr = x + (b * SS + s) * II;
    const float* wr = W_ih + j * II;
    float acc = b_ih[j] + b_hh[j];
    #pragma unroll
    for (int k = 0; k < II; k += 4) {
        float4 xv = *(const float4*)(xr + k);
        float4 wv = *(const float4*)(wr + k);
        acc += xv.x * wv.x + xv.y * wv.y + xv.z * wv.z + xv.w * wv.w;
    }
    xw[idx] = acc;
}

// ---------------- Kernel 2: RNN recurrence, one block (1 wave) per batch ----
// h in registers (lane j holds h[j]); broadcast via v_readlane; no LDS/barriers.
// __launch_bounds__(64,1): raise VGPR budget so the W_hh row stays resident.
__global__ __launch_bounds__(64, 1) void k_rnn(const float* __restrict__ xw,
                                               const float* __restrict__ W_hh,
                                               float* __restrict__ hs) {
    int b = blockIdx.x;
    int j = threadIdx.x;
    float w[HH];
    #pragma unroll
    for (int k = 0; k < HH; k++) w[k] = W_hh[j * HH + k];

    float hv = 0.0f;
    float xv0 = xw[(0 * BB + b) * HH + j];
    float xv1 = xw[(1 * BB + b) * HH + j];
    for (int t = 0; t < SS; t++) {
        int tn = (t < SS - 2) ? t + 2 : t;
        float xnext = xw[(tn * BB + b) * HH + j];  // prefetch depth 2
        float a0 = xv0, a1 = 0.f, a2 = 0.f, a3 = 0.f;
        #pragma unroll
        for (int k = 0; k < HH; k += 4) {
            a0 = fmaf(w[k + 0], bcast(hv, k + 0), a0);
            a1 = fmaf(w[k + 1], bcast(hv, k + 1), a1);
            a2 = fmaf(w[k + 2], bcast(hv, k + 2), a2);
            a3 = fmaf(w[k + 3], bcast(hv, k + 3), a3);
        }
        hv = fast_tanh((a0 + a1) + (a2 + a3));
        hs[(t * BB + b) * HH + j] = hv;   // fire-and-forget
        xv0 = xv1;
        xv1 = xnext;
    }
}

// ---------------- Kernel 3: tiled GEMM  C[M,N] = A[M,K] @ W[N,K]^T + bias ----
template<int K, bool RELU>
__global__ __launch_bounds__(256) void k_gemm(const float* __restrict__ A,
                                              const float* __restrict__ W,
                                              const float* __restrict__ bias,
                                              float* __restrict__ C, int N) {
    __shared__ float As[32][68];
    __shared__ float Ws[32][68];
    int tid = threadIdx.x;
    int tx = tid & 15, ty = tid >> 4;
    int rowBase = blockIdx.x * 64, colBase = blockIdx.y * 64;

    float acc[4][4];
    #pragma unroll
    for (int j2 = 0; j2 < 4; j2++) {
        float bv = bias[colBase + tx * 4 + j2];
        #pragma unroll
        for (int i2 = 0; i2 < 4; i2++) acc[i2][j2] = bv;
    }

    for (int kb = 0; kb < K; kb += 32) {
        #pragma unroll
        for (int u = 0; u < 2; u++) {
            int f = tid + u * 256;       // 0..511
            int r = f >> 3;              // 0..63
            int kk = (f & 7) * 4;
            float4 av = *(const float4*)(A + (size_t)(rowBase + r) * K + kb + kk);
            float4 wv = *(const float4*)(W + (size_t)(colBase + r) * K + kb + kk);
            As[kk + 0][r] = av.x; As[kk + 1][r] = av.y;
            As[kk + 2][r] = av.z; As[kk + 3][r] = av.w;
            Ws[kk + 0][r] = wv.x; Ws[kk + 1][r] = wv.y;
            Ws[kk + 2][r] = wv.z; Ws[kk + 3][r] = wv.w;
        }
        __syncthreads();
        #pragma unroll
        for (int kk = 0; kk < 32; kk++) {
            float4 a = *(const float4*)(&As[kk][ty * 4]);
            float4 w = *(const float4*)(&Ws[kk][tx * 4]);
            acc[0][0] += a.x * w.x; acc[0][1] += a.x * w.y;
            acc[0][2] += a.x * w.z; acc[0][3] += a.x * w.w;
            acc[1][0] += a.y * w.x; acc[1][1] += a.y * w.y;
            acc[1][2] += a.y * w.z; acc[1][3] += a.y * w.w;
            acc[2][0] += a.z * w.x; acc[2][1] += a.z * w.y;
            acc[2][2] += a.z * w.z; acc[2][3] += a.z * w.w;
            acc[3][0] += a.w * w.x; acc[3][1] += a.w * w.y;
            acc[3][2] += a.w * w.z; acc[3][3] += a.w * w.w;
        }
        __syncthreads();
    }
    #pragma unroll
    for (int i2 = 0; i2 < 4; i2++) {
        float4 o;
        o.x = acc[i2][0]; o.y = acc[i2][1]; o.z = acc[i2][2]; o.w = acc[i2][3];
        if (RELU) {
            o.x = fmaxf(o.x, 0.f); o.y = fmaxf(o.y, 0.f);
            o.z = fmaxf(o.z, 0.f); o.w = fmaxf(o.w, 0.f);
        }
        *(float4*)(C + (size_t)(rowBase + ty * 4 + i2) * N + colBase + tx * 4) = o;
    }
}

// ---------------- Kernel 4: MFMA flash attention, one block per (b, head) ---
// Per (b,h): Q,K,V are 512x16. bf16 mfma_f32_16x16x32 with hd=16 zero-padded
// to K=32 (zeros materialized in LDS -> no divergence). Each wave owns a
// 128-row Q strip; all 32 score tiles (vs 512 keys) live in registers
// (32 x f32x4 = 128 VGPRs), so softmax is EXACT single-pass (no online
// rescaling). P goes C-layout -> LDS (wave-private, double-buffered) ->
// A-layout for the PV mfmas (m120-verified mappings:
//   A[m=lane&15][k=quad*8+j], C/D: col=lane&15, row=quad*4+reg).
// LDS: K 32KB (dims padded to 32) + Vt 16KB + P 16KB = 64KB -> 2 blocks/CU.
__global__ __launch_bounds__(256, 2) void k_attn(const float* __restrict__ qkv,
                                                 float* __restrict__ ctx) {
    int bh = blockIdx.x;
    int b = bh >> 3, h = bh & 7;
    __shared__ short Klds[SS * 32];        // [t][32], dims 16..31 = 0
    __shared__ short Vt[HDIM][SS];         // [d][t]
    __shared__ short Pb[4][2][16 * 64];    // [wave][dbuf][qrow][64 keys]
    int tid = threadIdx.x;

    // ---- stage K (bf16, zero-padded dims) and V^T (bf16) into LDS ----
    for (int t = tid; t < SS; t += 256) {
        const float* base = qkv + (size_t)(t * BB + b) * 384 + h * 16;
        float4 k0 = *(const float4*)(base + 128);
        float4 k1 = *(const float4*)(base + 132);
        float4 k2 = *(const float4*)(base + 136);
        float4 k3 = *(const float4*)(base + 140);
        float4 v0 = *(const float4*)(base + 256);
        float4 v1 = *(const float4*)(base + 260);
        float4 v2 = *(const float4*)(base + 264);
        float4 v3 = *(const float4*)(base + 268);
        short* kd = &Klds[t * 32];
        kd[0]=f2bf(k0.x); kd[1]=f2bf(k0.y); kd[2]=f2bf(k0.z); kd[3]=f2bf(k0.w);
        kd[4]=f2bf(k1.x); kd[5]=f2bf(k1.y); kd[6]=f2bf(k1.z); kd[7]=f2bf(k1.w);
        kd[8]=f2bf(k2.x); kd[9]=f2bf(k2.y); kd[10]=f2bf(k2.z); kd[11]=f2bf(k2.w);
        kd[12]=f2bf(k3.x); kd[13]=f2bf(k3.y); kd[14]=f2bf(k3.z); kd[15]=f2bf(k3.w);
        *(int4*)&kd[16] = make_int4(0, 0, 0, 0);
        *(int4*)&kd[24] = make_int4(0, 0, 0, 0);
        Vt[0][t]=f2bf(v0.x);  Vt[1][t]=f2bf(v0.y);  Vt[2][t]=f2bf(v0.z);  Vt[3][t]=f2bf(v0.w);
        Vt[4][t]=f2bf(v1.x);  Vt[5][t]=f2bf(v1.y);  Vt[6][t]=f2bf(v1.z);  Vt[7][t]=f2bf(v1.w);
        Vt[8][t]=f2bf(v2.x);  Vt[9][t]=f2bf(v2.y);  Vt[10][t]=f2bf(v2.z); Vt[11][t]=f2bf(v2.w);
        Vt[12][t]=f2bf(v3.x); Vt[13][t]=f2bf(v3.y); Vt[14][t]=f2bf(v3.z); Vt[15][t]=f2bf(v3.w);
    }
    __syncthreads();

    int wid = tid >> 6, lane = tid & 63;
    int col = lane & 15, quad = lane >> 4;
    // fold score scale (1/sqrt(16)) and log2(e) into Q so p = exp2(S - m)
    const float qscale = 0.25f * 1.44269504f;

    for (int sub = 0; sub < 8; sub++) {
        int q0 = wid * 128 + sub * 16;

        // Q A-fragment: row = lane&15, k(dim) = quad*8+j; quads 2,3 -> zero pad
        bf16x8 qf = (bf16x8)(short)0;
        if (quad < 2) {
            const float* qsrc = qkv + (size_t)((q0 + col) * BB + b) * 384 + h * 16 + quad * 8;
            float4 qa = *(const float4*)qsrc;
            float4 qb = *(const float4*)(qsrc + 4);
            qf[0]=f2bf(qa.x*qscale); qf[1]=f2bf(qa.y*qscale);
            qf[2]=f2bf(qa.z*qscale); qf[3]=f2bf(qa.w*qscale);
            qf[4]=f2bf(qb.x*qscale); qf[5]=f2bf(qb.y*qscale);
            qf[6]=f2bf(qb.z*qscale); qf[7]=f2bf(qb.w*qscale);
        }

        // ---- scores: 32 tiles of 16q x 16keys, all kept in registers ----
        f32x4 S[32];
        #pragma unroll
        for (int kt = 0; kt < 32; kt++) {
            bf16x8 kf = *(const bf16x8*)&Klds[(kt * 16 + col) * 32 + quad * 8];
            f32x4 z = {0.f, 0.f, 0.f, 0.f};
            S[kt] = __builtin_amdgcn_mfma_f32_16x16x32_bf16(qf, kf, z, 0, 0, 0);
        }

        // ---- exact softmax over all 512 keys (rows = 4*quad + r) ----
        float mx[4], sm[4];
        #pragma unroll
        for (int r = 0; r < 4; r++) {
            float m = S[0][r];
            #pragma unroll
            for (int kt = 1; kt < 32; kt++) m = fmaxf(m, S[kt][r]);
            #pragma unroll
            for (int off = 1; off < 16; off <<= 1) m = fmaxf(m, __shfl_xor(m, off, 64));
            mx[r] = m;
        }
        #pragma unroll
        for (int r = 0; r < 4; r++) {
            float s = 0.f;
            #pragma unroll
            for (int kt = 0; kt < 32; kt++) {
                float p = exp2f(S[kt][r] - mx[r]);
                S[kt][r] = p;
                s += p;
            }
            #pragma unroll
            for (int off = 1; off < 16; off <<= 1) s += __shfl_xor(s, off, 64);
            sm[r] = s;
        }

        // ---- PV: chunks of 64 keys; P via wave-private LDS (C->A layout) ----
        f32x4 O = {0.f, 0.f, 0.f, 0.f};
        #pragma unroll
        for (int c = 0; c < 8; c++) {
            short* pbuf = &Pb[wid][c & 1][0];
            #pragma unroll
            for (int kk = 0; kk < 4; kk++) {
                int kt = c * 4 + kk;
                #pragma unroll
                for (int r = 0; r < 4; r++)
                    pbuf[(4 * quad + r) * 64 + kk * 16 + col] = f2bf(S[kt][r]);
            }
            #pragma unroll
            for (int half = 0; half < 2; half++) {
                int tbase = c * 64 + half * 32;
                bf16x8 pf = *(const bf16x8*)&pbuf[col * 64 + half * 32 + quad * 8];
                bf16x8 vf = *(const bf16x8*)&Vt[col][tbase + quad * 8];
                O = __builtin_amdgcn_mfma_f32_16x16x32_bf16(pf, vf, O, 0, 0, 0);
            }
        }

        // ---- normalize + store (O: row=4*quad+r (q), col=lane&15 (dim)) ----
        #pragma unroll
        for (int r = 0; r < 4; r++) {
            float inv = __builtin_amdgcn_rcpf(sm[r]);
            int q = q0 + 4 * quad + r;
            ctx[(size_t)(q * BB + b) * DD + h * 16 + col] = O[r] * inv;
        }
    }
}

// ---------------- Kernel 5: out = LayerNorm(a + b) * g + be (row = D=128) ---
__global__ __launch_bounds__(256) void k_add_ln(const float* __restrict__ a,
                                                const float* __restrict__ bres,
                                                const float* __restrict__ g,
                                                const float* __restrict__ be,
                                                float* __restrict__ out) {
    int row = blockIdx.x * 4 + (threadIdx.x >> 6);
    int lane = threadIdx.x & 63;
    const float* ar = a + (size_t)row * DD;
    const float* br = bres + (size_t)row * DD;
    float v0 = ar[lane] + br[lane];
    float v1 = ar[lane + 64] + br[lane + 64];
    float sum = v0 + v1;
    #pragma unroll
    for (int off = 32; off; off >>= 1) sum += __shfl_xor(sum, off, 64);
    float mu = sum * (1.0f / 128.0f);
    float d0 = v0 - mu, d1 = v1 - mu;
    float vs = d0 * d0 + d1 * d1;
    #pragma unroll
    for (int off = 32; off; off >>= 1) vs += __shfl_xor(vs, off, 64);
    float rstd = rsqrtf(vs * (1.0f / 128.0f) + 1e-5f);
    float* orow = out + (size_t)row * DD;
    orow[lane]      = d0 * rstd * g[lane] + be[lane];
    orow[lane + 64] = d1 * rstd * g[lane + 64] + be[lane + 64];
}

// ---------------- Kernel 6: mean-pool over S --------------------------------
__global__ __launch_bounds__(128) void k_pool(const float* __restrict__ out_ln,
                                              float* __restrict__ pooled) {
    int b = blockIdx.x;
    int d = threadIdx.x;
    float sum = 0.f;
    #pragma unroll 8
    for (int s = 0; s < SS; s++) sum += out_ln[(size_t)(s * BB + b) * DD + d];
    pooled[b * DD + d] = sum * (1.0f / SS);
}

// ---------------- Kernel 7: head  out = tanh(pooled @ Wf^T + bf) ------------
__global__ __launch_bounds__(64) void k_final(const float* __restrict__ pooled,
                                              const float* __restrict__ Wf,
                                              const float* __restrict__ bf,
                                              float* __restrict__ out) {
    int idx = blockIdx.x * 64 + threadIdx.x;  // 2048
    int b = idx >> 5, i = idx & 31;
    const float* pr = pooled + b * DD;
    const float* wr = Wf + i * DD;
    float acc = bf[i];
    #pragma unroll
    for (int k = 0; k < DD; k += 4) {
        float4 p = *(const float4*)(pr + k);
        float4 w = *(const float4*)(wr + k);
        acc += p.x * w.x + p.y * w.y + p.z * w.z + p.w * w.w;
    }
    out[idx] = fast_tanh(acc);
}

extern "C" void kernel_launch(void* const* d_in, const int* in_sizes, int n_in,
                              void* d_out, int out_size, void* d_ws, size_t ws_size,
                              hipStream_t stream) {
    const float* x    = (const float*)d_in[0];
    const float* W_ih = (const float*)d_in[1];
    const float* b_ih = (const float*)d_in[2];
    const float* W_hh = (const float*)d_in[3];
    const float* b_hh = (const float*)d_in[4];
    const float* Wp   = (const float*)d_in[5];
    const float* bp   = (const float*)d_in[6];
    const float* Wqkv = (const float*)d_in[7];
    const float* bqkv = (const float*)d_in[8];
    const float* Wo   = (const float*)d_in[9];
    const float* bo   = (const float*)d_in[10];
    const float* g1   = (const float*)d_in[11];
    const float* be1  = (const float*)d_in[12];
    const float* W1   = (const float*)d_in[13];
    const float* b1   = (const float*)d_in[14];
    const float* W2   = (const float*)d_in[15];
    const float* b2   = (const float*)d_in[16];
    const float* g2   = (const float*)d_in[17];
    const float* be2  = (const float*)d_in[18];
    const float* gn   = (const float*)d_in[19];
    const float* bn   = (const float*)d_in[20];
    const float* Wf   = (const float*)d_in[21];
    const float* bf   = (const float*)d_in[22];
    float* out = (float*)d_out;
    float* ws  = (float*)d_ws;

    // workspace layout (floats); regions reused once dead. Needs ~128.1 MB.
    float* proj     = ws + 0;          // 4M   [phase 3 .. end]
    float* qkv      = ws + 4194304;    // 12.6M [phase 4 .. 5]
    float* outln    = ws + 4194304;    // 4M   (reuses qkv, phase 11+)
    float* x2       = ws + 8388608;    // 4M   (reuses qkv, phase 10+)
    float* xw       = ws + 16777216;   // 2M   [phase 1 .. 2]
    float* hsbuf    = ws + 18874368;   // 2M   [phase 2 .. 3]
    float* ctx      = ws + 16777216;   // 4M   (reuses xw+hs, phase 5 .. 6)
    float* ff2      = ws + 16777216;   // 4M   (reuses ctx, phase 9 .. 10)
    float* x1       = ws + 20971520;   // 4M   [phase 7 .. 10]
    float* attn_out = ws + 25165824;   // 4M   [phase 6 .. 7]
    float* ff1      = ws + 25165824;   // 8.4M (reuses attn_out, phase 8 .. 9)
    float* pooled   = ws + 33554432;   // 8K

    k_xw<<<8192, 256, 0, stream>>>(x, W_ih, b_ih, b_hh, xw);
    k_rnn<<<64, 64, 0, stream>>>(xw, W_hh, hsbuf);
    k_gemm<64,  false><<<dim3(512, 2), 256, 0, stream>>>(hsbuf, Wp, bp, proj, 128);
    k_gemm<128, false><<<dim3(512, 6), 256, 0, stream>>>(proj, Wqkv, bqkv, qkv, 384);
    k_attn<<<512, 256, 0, stream>>>(qkv, ctx);
    k_gemm<128, false><<<dim3(512, 2), 256, 0, stream>>>(ctx, Wo, bo, attn_out, 128);
    k_add_ln<<<8192, 256, 0, stream>>>(proj, attn_out, g1, be1, x1);
    k_gemm<128, true ><<<dim3(512, 4), 256, 0, stream>>>(x1, W1, b1, ff1, 256);
    k_gemm<256, false><<<dim3(512, 2), 256, 0, stream>>>(ff1, W2, b2, ff2, 128);
    k_add_ln<<<8192, 256, 0, stream>>>(x1, ff2, g2, be2, x2);
    k_add_ln<<<8192, 256, 0, stream>>>(x2, proj, gn, bn, outln);
    k_pool<<<64, 128, 0, stream>>>(outln, pooled);
    k_final<<<32, 64, 0, stream>>>(pooled, Wf, bf, out);
}

// Round 5
// 469.022 us; speedup vs baseline: 1.7317x; 1.1663x over previous
//
#include <hip/hip_runtime.h>
#include <hip/hip_bf16.h>

#define BB 64
#define SS 512
#define II 32
#define HH 64
#define DD 128
#define FF 256
#define NHEAD 8
#define HDIM 16
#define NTOK (SS*BB)   // 32768

typedef short bf16x8 __attribute__((ext_vector_type(8)));
typedef float f32x4  __attribute__((ext_vector_type(4)));

__device__ __forceinline__ float fast_tanh(float x) {
    float ax = fabsf(x);
    float e = __expf(-2.0f * ax);
    float r = (1.0f - e) * __builtin_amdgcn_rcpf(1.0f + e);
    return copysignf(r, x);
}

// broadcast lane `lane`'s value of v to all lanes (const lane -> v_readlane_b32)
__device__ __forceinline__ float bcast(float v, int lane) {
    return __int_as_float(__builtin_amdgcn_readlane(__float_as_int(v), lane));
}

// fp32 -> bf16 bits, round-to-nearest-even
__device__ __forceinline__ short f2bf(float x) {
    unsigned u = __float_as_uint(x);
    return (short)((u + 0x7FFFu + ((u >> 16) & 1u)) >> 16);
}

// ---------------- Kernel 1: xw = x @ W_ih^T + b_ih + b_hh, layout (S,B,H) ----
__global__ __launch_bounds__(256) void k_xw(const float* __restrict__ x,
                                            const float* __restrict__ W_ih,
                                            const float* __restrict__ b_ih,
                                            const float* __restrict__ b_hh,
                                            float* __restrict__ xw) {
    int idx = blockIdx.x * 256 + threadIdx.x;  // over S*B*H = 2M
    int j  = idx & (HH - 1);
    int sb = idx >> 6;          // s*B + b
    int s  = sb >> 6;           // / B
    int b  = sb & (BB - 1);
    const float* xr = x + (b * SS + s) * II;
    const float* wr = W_ih + j * II;
    float acc = b_ih[j] + b_hh[j];
    #pragma unroll
    for (int k = 0; k < II; k += 4) {
        float4 xv = *(const float4*)(xr + k);
        float4 wv = *(const float4*)(wr + k);
        acc += xv.x * wv.x + xv.y * wv.y + xv.z * wv.z + xv.w * wv.w;
    }
    xw[idx] = acc;
}

// ---------------- Kernel 2: RNN recurrence, one block (1 wave) per batch ----
__global__ __launch_bounds__(64, 1) void k_rnn(const float* __restrict__ xw,
                                               const float* __restrict__ W_hh,
                                               float* __restrict__ hs) {
    int b = blockIdx.x;
    int j = threadIdx.x;
    float w[HH];
    #pragma unroll
    for (int k = 0; k < HH; k++) w[k] = W_hh[j * HH + k];

    float hv = 0.0f;
    float xv0 = xw[(0 * BB + b) * HH + j];
    float xv1 = xw[(1 * BB + b) * HH + j];
    for (int t = 0; t < SS; t++) {
        int tn = (t < SS - 2) ? t + 2 : t;
        float xnext = xw[(tn * BB + b) * HH + j];  // prefetch depth 2
        float a0 = xv0, a1 = 0.f, a2 = 0.f, a3 = 0.f;
        #pragma unroll
        for (int k = 0; k < HH; k += 4) {
            a0 = fmaf(w[k + 0], bcast(hv, k + 0), a0);
            a1 = fmaf(w[k + 1], bcast(hv, k + 1), a1);
            a2 = fmaf(w[k + 2], bcast(hv, k + 2), a2);
            a3 = fmaf(w[k + 3], bcast(hv, k + 3), a3);
        }
        hv = fast_tanh((a0 + a1) + (a2 + a3));
        hs[(t * BB + b) * HH + j] = hv;   // fire-and-forget
        xv0 = xv1;
        xv1 = xnext;
    }
}

// ---------------- Kernel 3: bf16 MFMA GEMM  C[M,N] = A[M,K] @ W[N,K]^T + b --
// Block: 256 thr (4 waves), tile M=128 x N=64, BK=32. fp32 inputs are
// converted to bf16 during LDS staging (no weight pre-pass). Fragment
// layouts identical to the verified k_attn QK^T pattern:
//   A-op frag [row][k=quad*8+j]; mfma(af, wf) = A.W^T; C/D col=lane&15,
//   row=quad*4+reg. LDS rows padded to 40 bf16 (80B) to break the
//   power-of-2 stride bank pattern (8-way -> 2-way, free per m136).
// Wave w computes rows [32w, 32w+32) x all 64 cols: 2x4 acc tiles.
template<int K, bool RELU>
__global__ __launch_bounds__(256) void k_gemm_mfma(const float* __restrict__ A,
                                                   const float* __restrict__ W,
                                                   const float* __restrict__ bias,
                                                   float* __restrict__ C, int N) {
    __shared__ short As[128 * 40];
    __shared__ short Ws[64 * 40];
    int tid = threadIdx.x;
    int wid = tid >> 6, lane = tid & 63;
    int col = lane & 15, quad = lane >> 4;
    int rowBase = blockIdx.x * 128, colBase = blockIdx.y * 64;

    // acc init with bias (bias depends on col only)
    f32x4 acc[2][4];
    #pragma unroll
    for (int nt = 0; nt < 4; nt++) {
        float bv = bias[colBase + nt * 16 + col];
        #pragma unroll
        for (int mt = 0; mt < 2; mt++) {
            acc[mt][nt][0] = bv; acc[mt][nt][1] = bv;
            acc[mt][nt][2] = bv; acc[mt][nt][3] = bv;
        }
    }

    // staging assignments (fixed per thread)
    int arow = tid >> 1, akb = (tid & 1) * 16;      // A: 16 floats each
    int wrow = tid >> 2, wkb = (tid & 3) * 8;       // W: 8 floats each

    for (int kb = 0; kb < K; kb += 32) {
        // ---- stage A tile 128x32 (fp32 -> bf16) ----
        {
            const float4* ap = (const float4*)(A + (size_t)(rowBase + arow) * K + kb + akb);
            float4 v0 = ap[0], v1 = ap[1], v2 = ap[2], v3 = ap[3];
            short t0[8], t1[8];
            t0[0]=f2bf(v0.x); t0[1]=f2bf(v0.y); t0[2]=f2bf(v0.z); t0[3]=f2bf(v0.w);
            t0[4]=f2bf(v1.x); t0[5]=f2bf(v1.y); t0[6]=f2bf(v1.z); t0[7]=f2bf(v1.w);
            t1[0]=f2bf(v2.x); t1[1]=f2bf(v2.y); t1[2]=f2bf(v2.z); t1[3]=f2bf(v2.w);
            t1[4]=f2bf(v3.x); t1[5]=f2bf(v3.y); t1[6]=f2bf(v3.z); t1[7]=f2bf(v3.w);
            *(int4*)&As[arow * 40 + akb]     = *(int4*)t0;
            *(int4*)&As[arow * 40 + akb + 8] = *(int4*)t1;
        }
        // ---- stage W tile 64x32 (fp32 -> bf16) ----
        {
            const float4* wp = (const float4*)(W + (size_t)(colBase + wrow) * K + kb + wkb);
            float4 v0 = wp[0], v1 = wp[1];
            short t0[8];
            t0[0]=f2bf(v0.x); t0[1]=f2bf(v0.y); t0[2]=f2bf(v0.z); t0[3]=f2bf(v0.w);
            t0[4]=f2bf(v1.x); t0[5]=f2bf(v1.y); t0[6]=f2bf(v1.z); t0[7]=f2bf(v1.w);
            *(int4*)&Ws[wrow * 40 + wkb] = *(int4*)t0;
        }
        __syncthreads();

        bf16x8 af[2], wf[4];
        #pragma unroll
        for (int mt = 0; mt < 2; mt++)
            af[mt] = *(const bf16x8*)&As[(wid * 32 + mt * 16 + col) * 40 + quad * 8];
        #pragma unroll
        for (int nt = 0; nt < 4; nt++)
            wf[nt] = *(const bf16x8*)&Ws[(nt * 16 + col) * 40 + quad * 8];
        #pragma unroll
        for (int mt = 0; mt < 2; mt++)
            #pragma unroll
            for (int nt = 0; nt < 4; nt++)
                acc[mt][nt] = __builtin_amdgcn_mfma_f32_16x16x32_bf16(af[mt], wf[nt], acc[mt][nt], 0, 0, 0);
        __syncthreads();
    }

    // ---- epilogue: scattered dword stores (64B runs per quad) ----
    #pragma unroll
    for (int mt = 0; mt < 2; mt++) {
        #pragma unroll
        for (int r = 0; r < 4; r++) {
            int m = rowBase + wid * 32 + mt * 16 + quad * 4 + r;
            float* crow = C + (size_t)m * N + colBase;
            #pragma unroll
            for (int nt = 0; nt < 4; nt++) {
                float v = acc[mt][nt][r];
                if (RELU) v = fmaxf(v, 0.f);
                crow[nt * 16 + col] = v;
            }
        }
    }
}

// ---------------- Kernel 4: MFMA flash attention, one block per (b, head) ---
__global__ __launch_bounds__(256, 2) void k_attn(const float* __restrict__ qkv,
                                                 float* __restrict__ ctx) {
    int bh = blockIdx.x;
    int b = bh >> 3, h = bh & 7;
    __shared__ short Klds[SS * 32];        // [t][32], dims 16..31 = 0
    __shared__ short Vt[HDIM][SS];         // [d][t]
    __shared__ short Pb[4][2][16 * 64];    // [wave][dbuf][qrow][64 keys]
    int tid = threadIdx.x;

    for (int t = tid; t < SS; t += 256) {
        const float* base = qkv + (size_t)(t * BB + b) * 384 + h * 16;
        float4 k0 = *(const float4*)(base + 128);
        float4 k1 = *(const float4*)(base + 132);
        float4 k2 = *(const float4*)(base + 136);
        float4 k3 = *(const float4*)(base + 140);
        float4 v0 = *(const float4*)(base + 256);
        float4 v1 = *(const float4*)(base + 260);
        float4 v2 = *(const float4*)(base + 264);
        float4 v3 = *(const float4*)(base + 268);
        short* kd = &Klds[t * 32];
        kd[0]=f2bf(k0.x); kd[1]=f2bf(k0.y); kd[2]=f2bf(k0.z); kd[3]=f2bf(k0.w);
        kd[4]=f2bf(k1.x); kd[5]=f2bf(k1.y); kd[6]=f2bf(k1.z); kd[7]=f2bf(k1.w);
        kd[8]=f2bf(k2.x); kd[9]=f2bf(k2.y); kd[10]=f2bf(k2.z); kd[11]=f2bf(k2.w);
        kd[12]=f2bf(k3.x); kd[13]=f2bf(k3.y); kd[14]=f2bf(k3.z); kd[15]=f2bf(k3.w);
        *(int4*)&kd[16] = make_int4(0, 0, 0, 0);
        *(int4*)&kd[24] = make_int4(0, 0, 0, 0);
        Vt[0][t]=f2bf(v0.x);  Vt[1][t]=f2bf(v0.y);  Vt[2][t]=f2bf(v0.z);  Vt[3][t]=f2bf(v0.w);
        Vt[4][t]=f2bf(v1.x);  Vt[5][t]=f2bf(v1.y);  Vt[6][t]=f2bf(v1.z);  Vt[7][t]=f2bf(v1.w);
        Vt[8][t]=f2bf(v2.x);  Vt[9][t]=f2bf(v2.y);  Vt[10][t]=f2bf(v2.z); Vt[11][t]=f2bf(v2.w);
        Vt[12][t]=f2bf(v3.x); Vt[13][t]=f2bf(v3.y); Vt[14][t]=f2bf(v3.z); Vt[15][t]=f2bf(v3.w);
    }
    __syncthreads();

    int wid = tid >> 6, lane = tid & 63;
    int col = lane & 15, quad = lane >> 4;
    const float qscale = 0.25f * 1.44269504f;

    for (int sub = 0; sub < 8; sub++) {
        int q0 = wid * 128 + sub * 16;

        bf16x8 qf = (bf16x8)(short)0;
        if (quad < 2) {
            const float* qsrc = qkv + (size_t)((q0 + col) * BB + b) * 384 + h * 16 + quad * 8;
            float4 qa = *(const float4*)qsrc;
            float4 qb = *(const float4*)(qsrc + 4);
            qf[0]=f2bf(qa.x*qscale); qf[1]=f2bf(qa.y*qscale);
            qf[2]=f2bf(qa.z*qscale); qf[3]=f2bf(qa.w*qscale);
            qf[4]=f2bf(qb.x*qscale); qf[5]=f2bf(qb.y*qscale);
            qf[6]=f2bf(qb.z*qscale); qf[7]=f2bf(qb.w*qscale);
        }

        f32x4 S[32];
        #pragma unroll
        for (int kt = 0; kt < 32; kt++) {
            bf16x8 kf = *(const bf16x8*)&Klds[(kt * 16 + col) * 32 + quad * 8];
            f32x4 z = {0.f, 0.f, 0.f, 0.f};
            S[kt] = __builtin_amdgcn_mfma_f32_16x16x32_bf16(qf, kf, z, 0, 0, 0);
        }

        float mx[4], sm[4];
        #pragma unroll
        for (int r = 0; r < 4; r++) {
            float m = S[0][r];
            #pragma unroll
            for (int kt = 1; kt < 32; kt++) m = fmaxf(m, S[kt][r]);
            #pragma unroll
            for (int off = 1; off < 16; off <<= 1) m = fmaxf(m, __shfl_xor(m, off, 64));
            mx[r] = m;
        }
        #pragma unroll
        for (int r = 0; r < 4; r++) {
            float s = 0.f;
            #pragma unroll
            for (int kt = 0; kt < 32; kt++) {
                float p = exp2f(S[kt][r] - mx[r]);
                S[kt][r] = p;
                s += p;
            }
            #pragma unroll
            for (int off = 1; off < 16; off <<= 1) s += __shfl_xor(s, off, 64);
            sm[r] = s;
        }

        f32x4 O = {0.f, 0.f, 0.f, 0.f};
        #pragma unroll
        for (int c = 0; c < 8; c++) {
            short* pbuf = &Pb[wid][c & 1][0];
            #pragma unroll
            for (int kk = 0; kk < 4; kk++) {
                int kt = c * 4 + kk;
                #pragma unroll
                for (int r = 0; r < 4; r++)
                    pbuf[(4 * quad + r) * 64 + kk * 16 + col] = f2bf(S[kt][r]);
            }
            #pragma unroll
            for (int half = 0; half < 2; half++) {
                int tbase = c * 64 + half * 32;
                bf16x8 pf = *(const bf16x8*)&pbuf[col * 64 + half * 32 + quad * 8];
                bf16x8 vf = *(const bf16x8*)&Vt[col][tbase + quad * 8];
                O = __builtin_amdgcn_mfma_f32_16x16x32_bf16(pf, vf, O, 0, 0, 0);
            }
        }

        #pragma unroll
        for (int r = 0; r < 4; r++) {
            float inv = __builtin_amdgcn_rcpf(sm[r]);
            int q = q0 + 4 * quad + r;
            ctx[(size_t)(q * BB + b) * DD + h * 16 + col] = O[r] * inv;
        }
    }
}

// ---------------- Kernel 5: out = LayerNorm(a + b) * g + be (row = D=128) ---
__global__ __launch_bounds__(256) void k_add_ln(const float* __restrict__ a,
                                                const float* __restrict__ bres,
                                                const float* __restrict__ g,
                                                const float* __restrict__ be,
                                                float* __restrict__ out) {
    int row = blockIdx.x * 4 + (threadIdx.x >> 6);
    int lane = threadIdx.x & 63;
    const float* ar = a + (size_t)row * DD;
    const float* br = bres + (size_t)row * DD;
    float v0 = ar[lane] + br[lane];
    float v1 = ar[lane + 64] + br[lane + 64];
    float sum = v0 + v1;
    #pragma unroll
    for (int off = 32; off; off >>= 1) sum += __shfl_xor(sum, off, 64);
    float mu = sum * (1.0f / 128.0f);
    float d0 = v0 - mu, d1 = v1 - mu;
    float vs = d0 * d0 + d1 * d1;
    #pragma unroll
    for (int off = 32; off; off >>= 1) vs += __shfl_xor(vs, off, 64);
    float rstd = rsqrtf(vs * (1.0f / 128.0f) + 1e-5f);
    float* orow = out + (size_t)row * DD;
    orow[lane]      = d0 * rstd * g[lane] + be[lane];
    orow[lane + 64] = d1 * rstd * g[lane + 64] + be[lane + 64];
}

// ---------------- Kernel 6: mean-pool over S --------------------------------
__global__ __launch_bounds__(128) void k_pool(const float* __restrict__ out_ln,
                                              float* __restrict__ pooled) {
    int b = blockIdx.x;
    int d = threadIdx.x;
    float sum = 0.f;
    #pragma unroll 8
    for (int s = 0; s < SS; s++) sum += out_ln[(size_t)(s * BB + b) * DD + d];
    pooled[b * DD + d] = sum * (1.0f / SS);
}

// ---------------- Kernel 7: head  out = tanh(pooled @ Wf^T + bf) ------------
__global__ __launch_bounds__(64) void k_final(const float* __restrict__ pooled,
                                              const float* __restrict__ Wf,
                                              const float* __restrict__ bf,
                                              float* __restrict__ out) {
    int idx = blockIdx.x * 64 + threadIdx.x;  // 2048
    int b = idx >> 5, i = idx & 31;
    const float* pr = pooled + b * DD;
    const float* wr = Wf + i * DD;
    float acc = bf[i];
    #pragma unroll
    for (int k = 0; k < DD; k += 4) {
        float4 p = *(const float4*)(pr + k);
        float4 w = *(const float4*)(wr + k);
        acc += p.x * w.x + p.y * w.y + p.z * w.z + p.w * w.w;
    }
    out[idx] = fast_tanh(acc);
}

extern "C" void kernel_launch(void* const* d_in, const int* in_sizes, int n_in,
                              void* d_out, int out_size, void* d_ws, size_t ws_size,
                              hipStream_t stream) {
    const float* x    = (const float*)d_in[0];
    const float* W_ih = (const float*)d_in[1];
    const float* b_ih = (const float*)d_in[2];
    const float* W_hh = (const float*)d_in[3];
    const float* b_hh = (const float*)d_in[4];
    const float* Wp   = (const float*)d_in[5];
    const float* bp   = (const float*)d_in[6];
    const float* Wqkv = (const float*)d_in[7];
    const float* bqkv = (const float*)d_in[8];
    const float* Wo   = (const float*)d_in[9];
    const float* bo   = (const float*)d_in[10];
    const float* g1   = (const float*)d_in[11];
    const float* be1  = (const float*)d_in[12];
    const float* W1   = (const float*)d_in[13];
    const float* b1   = (const float*)d_in[14];
    const float* W2   = (const float*)d_in[15];
    const float* b2   = (const float*)d_in[16];
    const float* g2   = (const float*)d_in[17];
    const float* be2  = (const float*)d_in[18];
    const float* gn   = (const float*)d_in[19];
    const float* bn   = (const float*)d_in[20];
    const float* Wf   = (const float*)d_in[21];
    const float* bf   = (const float*)d_in[22];
    float* out = (float*)d_out;
    float* ws  = (float*)d_ws;

    // workspace layout (floats); regions reused once dead. Needs ~128.1 MB.
    float* proj     = ws + 0;          // 4M   [phase 3 .. end]
    float* qkv      = ws + 4194304;    // 12.6M [phase 4 .. 5]
    float* outln    = ws + 4194304;    // 4M   (reuses qkv, phase 11+)
    float* x2       = ws + 8388608;    // 4M   (reuses qkv, phase 10+)
    float* xw       = ws + 16777216;   // 2M   [phase 1 .. 2]
    float* hsbuf    = ws + 18874368;   // 2M   [phase 2 .. 3]
    float* ctx      = ws + 16777216;   // 4M   (reuses xw+hs, phase 5 .. 6)
    float* ff2      = ws + 16777216;   // 4M   (reuses ctx, phase 9 .. 10)
    float* x1       = ws + 20971520;   // 4M   [phase 7 .. 10]
    float* attn_out = ws + 25165824;   // 4M   [phase 6 .. 7]
    float* ff1      = ws + 25165824;   // 8.4M (reuses attn_out, phase 8 .. 9)
    float* pooled   = ws + 33554432;   // 8K

    k_xw<<<8192, 256, 0, stream>>>(x, W_ih, b_ih, b_hh, xw);
    k_rnn<<<64, 64, 0, stream>>>(xw, W_hh, hsbuf);
    k_gemm_mfma<64,  false><<<dim3(256, 2), 256, 0, stream>>>(hsbuf, Wp, bp, proj, 128);
    k_gemm_mfma<128, false><<<dim3(256, 6), 256, 0, stream>>>(proj, Wqkv, bqkv, qkv, 384);
    k_attn<<<512, 256, 0, stream>>>(qkv, ctx);
    k_gemm_mfma<128, false><<<dim3(256, 2), 256, 0, stream>>>(ctx, Wo, bo, attn_out, 128);
    k_add_ln<<<8192, 256, 0, stream>>>(proj, attn_out, g1, be1, x1);
    k_gemm_mfma<128, true ><<<dim3(256, 4), 256, 0, stream>>>(x1, W1, b1, ff1, 256);
    k_gemm_mfma<256, false><<<dim3(256, 2), 256, 0, stream>>>(ff1, W2, b2, ff2, 128);
    k_add_ln<<<8192, 256, 0, stream>>>(x1, ff2, g2, be2, x2);
    k_add_ln<<<8192, 256, 0, stream>>>(x2, proj, gn, bn, outln);
    k_pool<<<64, 128, 0, stream>>>(outln, pooled);
    k_final<<<32, 64, 0, stream>>>(pooled, Wf, bf, out);
}

// Round 6
// 457.205 us; speedup vs baseline: 1.7764x; 1.0258x over previous
//
#include <hip/hip_runtime.h>
#include <hip/hip_bf16.h>

#define BB 64
#define SS 512
#define II 32
#define HH 64
#define DD 128
#define FF 256
#define NHEAD 8
#define HDIM 16
#define NTOK (SS*BB)   // 32768

typedef short bf16x8 __attribute__((ext_vector_type(8)));
typedef float f32x4  __attribute__((ext_vector_type(4)));

__device__ __forceinline__ float fast_tanh(float x) {
    float ax = fabsf(x);
    float e = __expf(-2.0f * ax);
    float r = (1.0f - e) * __builtin_amdgcn_rcpf(1.0f + e);
    return copysignf(r, x);
}

__device__ __forceinline__ float bcast(float v, int lane) {
    return __int_as_float(__builtin_amdgcn_readlane(__float_as_int(v), lane));
}

// fp32 -> bf16 bits, round-to-nearest-even
__device__ __forceinline__ short f2bf(float x) {
    unsigned u = __float_as_uint(x);
    return (short)((u + 0x7FFFu + ((u >> 16) & 1u)) >> 16);
}

// ---------------- Kernel 1: xw = x @ W_ih^T + b_ih + b_hh, layout (S,B,H) ----
__global__ __launch_bounds__(256) void k_xw(const float* __restrict__ x,
                                            const float* __restrict__ W_ih,
                                            const float* __restrict__ b_ih,
                                            const float* __restrict__ b_hh,
                                            float* __restrict__ xw) {
    int idx = blockIdx.x * 256 + threadIdx.x;  // over S*B*H = 2M
    int j  = idx & (HH - 1);
    int sb = idx >> 6;          // s*B + b
    int s  = sb >> 6;           // / B
    int b  = sb & (BB - 1);
    const float* xr = x + (b * SS + s) * II;
    const float* wr = W_ih + j * II;
    float acc = b_ih[j] + b_hh[j];
    #pragma unroll
    for (int k = 0; k < II; k += 4) {
        float4 xv = *(const float4*)(xr + k);
        float4 wv = *(const float4*)(wr + k);
        acc += xv.x * wv.x + xv.y * wv.y + xv.z * wv.z + xv.w * wv.w;
    }
    xw[idx] = acc;
}

// ---------------- Kernel 2: RNN recurrence, one block (1 wave) per batch ----
// h in registers (lane j holds h[j]); broadcast via v_readlane. The per-step
// h store goes to an LDS ring (lgkmcnt, NOT vmcnt) and is bulk-flushed to
// global every 64 steps -- vmcnt retires IN ORDER, so per-step global stores
// were blocking the xw-load waitcnt behind slow store retirement (R5: 630
// cyc/step vs ~300 issue floor). Stride 68 floats: step-writes conflict-free.
__global__ __launch_bounds__(64, 1) void k_rnn(const float* __restrict__ xw,
                                               const float* __restrict__ W_hh,
                                               float* __restrict__ hs) {
    int b = blockIdx.x;
    int j = threadIdx.x;
    float w[HH];
    #pragma unroll
    for (int k = 0; k < HH; k++) w[k] = W_hh[j * HH + k];

    __shared__ float hbuf[64 * 68];

    float hv = 0.0f;
    float xv0 = xw[(0 * BB + b) * HH + j];
    float xv1 = xw[(1 * BB + b) * HH + j];
    for (int t = 0; t < SS; t++) {
        int tn = (t < SS - 2) ? t + 2 : t;
        float xnext = xw[(tn * BB + b) * HH + j];  // prefetch depth 2
        float a0 = xv0, a1 = 0.f, a2 = 0.f, a3 = 0.f;
        #pragma unroll
        for (int k = 0; k < HH; k += 4) {
            a0 = fmaf(w[k + 0], bcast(hv, k + 0), a0);
            a1 = fmaf(w[k + 1], bcast(hv, k + 1), a1);
            a2 = fmaf(w[k + 2], bcast(hv, k + 2), a2);
            a3 = fmaf(w[k + 3], bcast(hv, k + 3), a3);
        }
        hv = fast_tanh((a0 + a1) + (a2 + a3));
        hbuf[(t & 63) * 68 + j] = hv;           // LDS ring (lgkmcnt only)
        if ((t & 63) == 63) {
            // lane j flushes local step j -> global step t-63+j (64 floats)
            int tg = t - 63 + j;
            const float* src = &hbuf[j * 68];
            float* dst = hs + (size_t)(tg * BB + b) * HH;
            #pragma unroll
            for (int c = 0; c < 16; c++) {
                float4 v4 = *(const float4*)&src[c * 4];
                *(float4*)&dst[c * 4] = v4;     // fire-and-forget, off-path
            }
        }
        xv0 = xv1;
        xv1 = xnext;
    }
}

// ---------------- Kernel 3: bf16 MFMA GEMM  C[M,N] = A[M,K] @ W[N,K]^T + b --
// 256 thr / 4 waves, tile M=128 x N=64, BK=32; fp32->bf16 fused into staging.
template<int K, bool RELU>
__global__ __launch_bounds__(256) void k_gemm_mfma(const float* __restrict__ A,
                                                   const float* __restrict__ W,
                                                   const float* __restrict__ bias,
                                                   float* __restrict__ C, int N) {
    __shared__ short As[128 * 40];
    __shared__ short Ws[64 * 40];
    int tid = threadIdx.x;
    int wid = tid >> 6, lane = tid & 63;
    int col = lane & 15, quad = lane >> 4;
    int rowBase = blockIdx.x * 128, colBase = blockIdx.y * 64;

    f32x4 acc[2][4];
    #pragma unroll
    for (int nt = 0; nt < 4; nt++) {
        float bv = bias[colBase + nt * 16 + col];
        #pragma unroll
        for (int mt = 0; mt < 2; mt++) {
            acc[mt][nt][0] = bv; acc[mt][nt][1] = bv;
            acc[mt][nt][2] = bv; acc[mt][nt][3] = bv;
        }
    }

    int arow = tid >> 1, akb = (tid & 1) * 16;      // A: 16 floats each
    int wrow = tid >> 2, wkb = (tid & 3) * 8;       // W: 8 floats each

    for (int kb = 0; kb < K; kb += 32) {
        {
            const float4* ap = (const float4*)(A + (size_t)(rowBase + arow) * K + kb + akb);
            float4 v0 = ap[0], v1 = ap[1], v2 = ap[2], v3 = ap[3];
            short t0[8], t1[8];
            t0[0]=f2bf(v0.x); t0[1]=f2bf(v0.y); t0[2]=f2bf(v0.z); t0[3]=f2bf(v0.w);
            t0[4]=f2bf(v1.x); t0[5]=f2bf(v1.y); t0[6]=f2bf(v1.z); t0[7]=f2bf(v1.w);
            t1[0]=f2bf(v2.x); t1[1]=f2bf(v2.y); t1[2]=f2bf(v2.z); t1[3]=f2bf(v2.w);
            t1[4]=f2bf(v3.x); t1[5]=f2bf(v3.y); t1[6]=f2bf(v3.z); t1[7]=f2bf(v3.w);
            *(int4*)&As[arow * 40 + akb]     = *(int4*)t0;
            *(int4*)&As[arow * 40 + akb + 8] = *(int4*)t1;
        }
        {
            const float4* wp = (const float4*)(W + (size_t)(colBase + wrow) * K + kb + wkb);
            float4 v0 = wp[0], v1 = wp[1];
            short t0[8];
            t0[0]=f2bf(v0.x); t0[1]=f2bf(v0.y); t0[2]=f2bf(v0.z); t0[3]=f2bf(v0.w);
            t0[4]=f2bf(v1.x); t0[5]=f2bf(v1.y); t0[6]=f2bf(v1.z); t0[7]=f2bf(v1.w);
            *(int4*)&Ws[wrow * 40 + wkb] = *(int4*)t0;
        }
        __syncthreads();

        bf16x8 af[2], wf[4];
        #pragma unroll
        for (int mt = 0; mt < 2; mt++)
            af[mt] = *(const bf16x8*)&As[(wid * 32 + mt * 16 + col) * 40 + quad * 8];
        #pragma unroll
        for (int nt = 0; nt < 4; nt++)
            wf[nt] = *(const bf16x8*)&Ws[(nt * 16 + col) * 40 + quad * 8];
        #pragma unroll
        for (int mt = 0; mt < 2; mt++)
            #pragma unroll
            for (int nt = 0; nt < 4; nt++)
                acc[mt][nt] = __builtin_amdgcn_mfma_f32_16x16x32_bf16(af[mt], wf[nt], acc[mt][nt], 0, 0, 0);
        __syncthreads();
    }

    #pragma unroll
    for (int mt = 0; mt < 2; mt++) {
        #pragma unroll
        for (int r = 0; r < 4; r++) {
            int m = rowBase + wid * 32 + mt * 16 + quad * 4 + r;
            float* crow = C + (size_t)m * N + colBase;
            #pragma unroll
            for (int nt = 0; nt < 4; nt++) {
                float v = acc[mt][nt][r];
                if (RELU) v = fmaxf(v, 0.f);
                crow[nt * 16 + col] = v;
            }
        }
    }
}

// ------- Kernels 3b/3c: GEMM (tile 128x128, N=DD) with fused LayerNorm ------
// Each quad (16 lanes) owns whole output rows -> LN row stats via in-lane
// 8-sum + 4-step shuffle butterfly (width 16, stays inside the quad).
template<int K, int NLN>
__global__ __launch_bounds__(256) void k_gemm_ln(const float* __restrict__ A,
                                                 const float* __restrict__ W,
                                                 const float* __restrict__ bias,
                                                 const float* __restrict__ res1,
                                                 const float* __restrict__ g1v,
                                                 const float* __restrict__ be1v,
                                                 const float* __restrict__ res2,
                                                 const float* __restrict__ g2v,
                                                 const float* __restrict__ be2v,
                                                 float* __restrict__ out) {
    __shared__ short As[128 * 40];
    __shared__ short Ws[128 * 40];
    int tid = threadIdx.x;
    int wid = tid >> 6, lane = tid & 63;
    int col = lane & 15, quad = lane >> 4;
    int rowBase = blockIdx.x * 128;

    f32x4 acc[2][8];
    #pragma unroll
    for (int nt = 0; nt < 8; nt++) {
        float bv = bias[nt * 16 + col];
        #pragma unroll
        for (int mt = 0; mt < 2; mt++) {
            acc[mt][nt][0] = bv; acc[mt][nt][1] = bv;
            acc[mt][nt][2] = bv; acc[mt][nt][3] = bv;
        }
    }

    int arow = tid >> 1, akb = (tid & 1) * 16;   // 16 floats each for A and W

    for (int kb = 0; kb < K; kb += 32) {
        {
            const float4* ap = (const float4*)(A + (size_t)(rowBase + arow) * K + kb + akb);
            float4 v0 = ap[0], v1 = ap[1], v2 = ap[2], v3 = ap[3];
            short t0[8], t1[8];
            t0[0]=f2bf(v0.x); t0[1]=f2bf(v0.y); t0[2]=f2bf(v0.z); t0[3]=f2bf(v0.w);
            t0[4]=f2bf(v1.x); t0[5]=f2bf(v1.y); t0[6]=f2bf(v1.z); t0[7]=f2bf(v1.w);
            t1[0]=f2bf(v2.x); t1[1]=f2bf(v2.y); t1[2]=f2bf(v2.z); t1[3]=f2bf(v2.w);
            t1[4]=f2bf(v3.x); t1[5]=f2bf(v3.y); t1[6]=f2bf(v3.z); t1[7]=f2bf(v3.w);
            *(int4*)&As[arow * 40 + akb]     = *(int4*)t0;
            *(int4*)&As[arow * 40 + akb + 8] = *(int4*)t1;
        }
        {
            const float4* wp = (const float4*)(W + (size_t)arow * K + kb + akb);
            float4 v0 = wp[0], v1 = wp[1], v2 = wp[2], v3 = wp[3];
            short t0[8], t1[8];
            t0[0]=f2bf(v0.x); t0[1]=f2bf(v0.y); t0[2]=f2bf(v0.z); t0[3]=f2bf(v0.w);
            t0[4]=f2bf(v1.x); t0[5]=f2bf(v1.y); t0[6]=f2bf(v1.z); t0[7]=f2bf(v1.w);
            t1[0]=f2bf(v2.x); t1[1]=f2bf(v2.y); t1[2]=f2bf(v2.z); t1[3]=f2bf(v2.w);
            t1[4]=f2bf(v3.x); t1[5]=f2bf(v3.y); t1[6]=f2bf(v3.z); t1[7]=f2bf(v3.w);
            *(int4*)&Ws[arow * 40 + akb]     = *(int4*)t0;
            *(int4*)&Ws[arow * 40 + akb + 8] = *(int4*)t1;
        }
        __syncthreads();

        bf16x8 af[2], wf[8];
        #pragma unroll
        for (int mt = 0; mt < 2; mt++)
            af[mt] = *(const bf16x8*)&As[(wid * 32 + mt * 16 + col) * 40 + quad * 8];
        #pragma unroll
        for (int nt = 0; nt < 8; nt++)
            wf[nt] = *(const bf16x8*)&Ws[(nt * 16 + col) * 40 + quad * 8];
        #pragma unroll
        for (int mt = 0; mt < 2; mt++)
            #pragma unroll
            for (int nt = 0; nt < 8; nt++)
                acc[mt][nt] = __builtin_amdgcn_mfma_f32_16x16x32_bf16(af[mt], wf[nt], acc[mt][nt], 0, 0, 0);
        __syncthreads();
    }

    // hoisted LN params (depend on column only)
    float ga[8], ba[8], gb[8], bb[8];
    #pragma unroll
    for (int nt = 0; nt < 8; nt++) {
        ga[nt] = g1v[nt * 16 + col]; ba[nt] = be1v[nt * 16 + col];
        if (NLN == 2) { gb[nt] = g2v[nt * 16 + col]; bb[nt] = be2v[nt * 16 + col]; }
    }

    #pragma unroll
    for (int mt = 0; mt < 2; mt++) {
        #pragma unroll
        for (int r = 0; r < 4; r++) {
            int m = rowBase + wid * 32 + mt * 16 + quad * 4 + r;
            const float* rr1 = res1 + (size_t)m * DD;
            float v[8];
            float s = 0.f;
            #pragma unroll
            for (int nt = 0; nt < 8; nt++) {
                v[nt] = acc[mt][nt][r] + rr1[nt * 16 + col];
                s += v[nt];
            }
            #pragma unroll
            for (int off = 1; off < 16; off <<= 1) s += __shfl_xor(s, off, 64);
            float mu = s * (1.0f / 128.0f);
            float vs = 0.f;
            #pragma unroll
            for (int nt = 0; nt < 8; nt++) { v[nt] -= mu; vs += v[nt] * v[nt]; }
            #pragma unroll
            for (int off = 1; off < 16; off <<= 1) vs += __shfl_xor(vs, off, 64);
            float rstd = rsqrtf(vs * (1.0f / 128.0f) + 1e-5f);
            #pragma unroll
            for (int nt = 0; nt < 8; nt++) v[nt] = v[nt] * rstd * ga[nt] + ba[nt];

            if (NLN == 2) {
                const float* rr2 = res2 + (size_t)m * DD;
                float s2 = 0.f;
                #pragma unroll
                for (int nt = 0; nt < 8; nt++) {
                    v[nt] += rr2[nt * 16 + col];
                    s2 += v[nt];
                }
                #pragma unroll
                for (int off = 1; off < 16; off <<= 1) s2 += __shfl_xor(s2, off, 64);
                float mu2 = s2 * (1.0f / 128.0f);
                float vs2 = 0.f;
                #pragma unroll
                for (int nt = 0; nt < 8; nt++) { v[nt] -= mu2; vs2 += v[nt] * v[nt]; }
                #pragma unroll
                for (int off = 1; off < 16; off <<= 1) vs2 += __shfl_xor(vs2, off, 64);
                float rstd2 = rsqrtf(vs2 * (1.0f / 128.0f) + 1e-5f);
                #pragma unroll
                for (int nt = 0; nt < 8; nt++) v[nt] = v[nt] * rstd2 * gb[nt] + bb[nt];
            }

            float* orow = out + (size_t)m * DD;
            #pragma unroll
            for (int nt = 0; nt < 8; nt++) orow[nt * 16 + col] = v[nt];
        }
    }
}

// ---------------- Kernel 4: MFMA flash attention, one block per (b, head) ---
__global__ __launch_bounds__(256, 2) void k_attn(const float* __restrict__ qkv,
                                                 float* __restrict__ ctx) {
    int bh = blockIdx.x;
    int b = bh >> 3, h = bh & 7;
    __shared__ short Klds[SS * 32];        // [t][32], dims 16..31 = 0
    __shared__ short Vt[HDIM][SS];         // [d][t]
    __shared__ short Pb[4][2][16 * 64];    // [wave][dbuf][qrow][64 keys]
    int tid = threadIdx.x;

    for (int t = tid; t < SS; t += 256) {
        const float* base = qkv + (size_t)(t * BB + b) * 384 + h * 16;
        float4 k0 = *(const float4*)(base + 128);
        float4 k1 = *(const float4*)(base + 132);
        float4 k2 = *(const float4*)(base + 136);
        float4 k3 = *(const float4*)(base + 140);
        float4 v0 = *(const float4*)(base + 256);
        float4 v1 = *(const float4*)(base + 260);
        float4 v2 = *(const float4*)(base + 264);
        float4 v3 = *(const float4*)(base + 268);
        short* kd = &Klds[t * 32];
        kd[0]=f2bf(k0.x); kd[1]=f2bf(k0.y); kd[2]=f2bf(k0.z); kd[3]=f2bf(k0.w);
        kd[4]=f2bf(k1.x); kd[5]=f2bf(k1.y); kd[6]=f2bf(k1.z); kd[7]=f2bf(k1.w);
        kd[8]=f2bf(k2.x); kd[9]=f2bf(k2.y); kd[10]=f2bf(k2.z); kd[11]=f2bf(k2.w);
        kd[12]=f2bf(k3.x); kd[13]=f2bf(k3.y); kd[14]=f2bf(k3.z); kd[15]=f2bf(k3.w);
        *(int4*)&kd[16] = make_int4(0, 0, 0, 0);
        *(int4*)&kd[24] = make_int4(0, 0, 0, 0);
        Vt[0][t]=f2bf(v0.x);  Vt[1][t]=f2bf(v0.y);  Vt[2][t]=f2bf(v0.z);  Vt[3][t]=f2bf(v0.w);
        Vt[4][t]=f2bf(v1.x);  Vt[5][t]=f2bf(v1.y);  Vt[6][t]=f2bf(v1.z);  Vt[7][t]=f2bf(v1.w);
        Vt[8][t]=f2bf(v2.x);  Vt[9][t]=f2bf(v2.y);  Vt[10][t]=f2bf(v2.z); Vt[11][t]=f2bf(v2.w);
        Vt[12][t]=f2bf(v3.x); Vt[13][t]=f2bf(v3.y); Vt[14][t]=f2bf(v3.z); Vt[15][t]=f2bf(v3.w);
    }
    __syncthreads();

    int wid = tid >> 6, lane = tid & 63;
    int col = lane & 15, quad = lane >> 4;
    const float qscale = 0.25f * 1.44269504f;

    for (int sub = 0; sub < 8; sub++) {
        int q0 = wid * 128 + sub * 16;

        bf16x8 qf = (bf16x8)(short)0;
        if (quad < 2) {
            const float* qsrc = qkv + (size_t)((q0 + col) * BB + b) * 384 + h * 16 + quad * 8;
            float4 qa = *(const float4*)qsrc;
            float4 qb = *(const float4*)(qsrc + 4);
            qf[0]=f2bf(qa.x*qscale); qf[1]=f2bf(qa.y*qscale);
            qf[2]=f2bf(qa.z*qscale); qf[3]=f2bf(qa.w*qscale);
            qf[4]=f2bf(qb.x*qscale); qf[5]=f2bf(qb.y*qscale);
            qf[6]=f2bf(qb.z*qscale); qf[7]=f2bf(qb.w*qscale);
        }

        f32x4 S[32];
        #pragma unroll
        for (int kt = 0; kt < 32; kt++) {
            bf16x8 kf = *(const bf16x8*)&Klds[(kt * 16 + col) * 32 + quad * 8];
            f32x4 z = {0.f, 0.f, 0.f, 0.f};
            S[kt] = __builtin_amdgcn_mfma_f32_16x16x32_bf16(qf, kf, z, 0, 0, 0);
        }

        float mx[4], sm[4];
        #pragma unroll
        for (int r = 0; r < 4; r++) {
            float m = S[0][r];
            #pragma unroll
            for (int kt = 1; kt < 32; kt++) m = fmaxf(m, S[kt][r]);
            #pragma unroll
            for (int off = 1; off < 16; off <<= 1) m = fmaxf(m, __shfl_xor(m, off, 64));
            mx[r] = m;
        }
        #pragma unroll
        for (int r = 0; r < 4; r++) {
            float s = 0.f;
            #pragma unroll
            for (int kt = 0; kt < 32; kt++) {
                float p = exp2f(S[kt][r] - mx[r]);
                S[kt][r] = p;
                s += p;
            }
            #pragma unroll
            for (int off = 1; off < 16; off <<= 1) s += __shfl_xor(s, off, 64);
            sm[r] = s;
        }

        f32x4 O = {0.f, 0.f, 0.f, 0.f};
        #pragma unroll
        for (int c = 0; c < 8; c++) {
            short* pbuf = &Pb[wid][c & 1][0];
            #pragma unroll
            for (int kk = 0; kk < 4; kk++) {
                int kt = c * 4 + kk;
                #pragma unroll
                for (int r = 0; r < 4; r++)
                    pbuf[(4 * quad + r) * 64 + kk * 16 + col] = f2bf(S[kt][r]);
            }
            #pragma unroll
            for (int half = 0; half < 2; half++) {
                int tbase = c * 64 + half * 32;
                bf16x8 pf = *(const bf16x8*)&pbuf[col * 64 + half * 32 + quad * 8];
                bf16x8 vf = *(const bf16x8*)&Vt[col][tbase + quad * 8];
                O = __builtin_amdgcn_mfma_f32_16x16x32_bf16(pf, vf, O, 0, 0, 0);
            }
        }

        #pragma unroll
        for (int r = 0; r < 4; r++) {
            float inv = __builtin_amdgcn_rcpf(sm[r]);
            int q = q0 + 4 * quad + r;
            ctx[(size_t)(q * BB + b) * DD + h * 16 + col] = O[r] * inv;
        }
    }
}

// ---------------- Kernel 5: fused mean-pool + head ---------------------------
__global__ __launch_bounds__(256) void k_poolfinal(const float* __restrict__ outln,
                                                   const float* __restrict__ Wf,
                                                   const float* __restrict__ bfv,
                                                   float* __restrict__ out) {
    int b = blockIdx.x;
    int tid = threadIdx.x;
    __shared__ float part[256];
    __shared__ float pooled[128];
    int d = tid & 127, half = tid >> 7;
    float s = 0.f;
    int s0 = half * 256;
    #pragma unroll 8
    for (int si = s0; si < s0 + 256; si++)
        s += outln[(size_t)(si * BB + b) * DD + d];
    part[tid] = s;
    __syncthreads();
    if (tid < 128) pooled[tid] = (part[tid] + part[tid + 128]) * (1.0f / SS);
    __syncthreads();
    if (tid < 32) {
        const float* wr = Wf + tid * DD;
        float acc = bfv[tid];
        #pragma unroll
        for (int k = 0; k < DD; k += 4) {
            float4 wv = *(const float4*)(wr + k);
            acc += pooled[k] * wv.x + pooled[k + 1] * wv.y
                 + pooled[k + 2] * wv.z + pooled[k + 3] * wv.w;
        }
        out[b * 32 + tid] = fast_tanh(acc);
    }
}

extern "C" void kernel_launch(void* const* d_in, const int* in_sizes, int n_in,
                              void* d_out, int out_size, void* d_ws, size_t ws_size,
                              hipStream_t stream) {
    const float* x    = (const float*)d_in[0];
    const float* W_ih = (const float*)d_in[1];
    const float* b_ih = (const float*)d_in[2];
    const float* W_hh = (const float*)d_in[3];
    const float* b_hh = (const float*)d_in[4];
    const float* Wp   = (const float*)d_in[5];
    const float* bp   = (const float*)d_in[6];
    const float* Wqkv = (const float*)d_in[7];
    const float* bqkv = (const float*)d_in[8];
    const float* Wo   = (const float*)d_in[9];
    const float* bo   = (const float*)d_in[10];
    const float* g1   = (const float*)d_in[11];
    const float* be1  = (const float*)d_in[12];
    const float* W1   = (const float*)d_in[13];
    const float* b1   = (const float*)d_in[14];
    const float* W2   = (const float*)d_in[15];
    const float* b2   = (const float*)d_in[16];
    const float* g2   = (const float*)d_in[17];
    const float* be2  = (const float*)d_in[18];
    const float* gn   = (const float*)d_in[19];
    const float* bn   = (const float*)d_in[20];
    const float* Wf   = (const float*)d_in[21];
    const float* bf   = (const float*)d_in[22];
    float* out = (float*)d_out;
    float* ws  = (float*)d_ws;

    // workspace layout (floats); regions reused once dead.
    float* proj   = ws + 0;          // 4M    [phase 3 .. end]
    float* qkv    = ws + 4194304;    // 12.6M [phase 4 .. 5]
    float* outln  = ws + 4194304;    // 4M    (reuses qkv, phase 8+)
    float* xw     = ws + 16777216;   // 2M    [phase 1 .. 2]
    float* hsbuf  = ws + 18874368;   // 2M    [phase 2 .. 3]
    float* ctx    = ws + 16777216;   // 4M    (reuses xw+hs, phase 5 .. 6)
    float* x1     = ws + 20971520;   // 4M    [phase 6 .. 8]
    float* ff1    = ws + 25165824;   // 8.4M  [phase 7 .. 8]

    k_xw<<<8192, 256, 0, stream>>>(x, W_ih, b_ih, b_hh, xw);
    k_rnn<<<64, 64, 0, stream>>>(xw, W_hh, hsbuf);
    k_gemm_mfma<64,  false><<<dim3(256, 2), 256, 0, stream>>>(hsbuf, Wp, bp, proj, 128);
    k_gemm_mfma<128, false><<<dim3(256, 6), 256, 0, stream>>>(proj, Wqkv, bqkv, qkv, 384);
    k_attn<<<512, 256, 0, stream>>>(qkv, ctx);
    // x1 = LN1(proj + ctx@Wo^T + bo)
    k_gemm_ln<128, 1><<<256, 256, 0, stream>>>(ctx, Wo, bo, proj, g1, be1,
                                               nullptr, nullptr, nullptr, x1);
    k_gemm_mfma<128, true ><<<dim3(256, 4), 256, 0, stream>>>(x1, W1, b1, ff1, 256);
    // outln = LN3( LN2(x1 + ff1@W2^T + b2) + proj )
    k_gemm_ln<256, 2><<<256, 256, 0, stream>>>(ff1, W2, b2, x1, g2, be2,
                                               proj, gn, bn, outln);
    k_poolfinal<<<64, 256, 0, stream>>>(outln, Wf, bf, out);
}